// Round 15
// baseline (158.056 us; speedup 1.0000x reference)
//
#include <hip/hip_runtime.h>
#include <hip/hip_bf16.h>

#define Bn 4
#define Tn 256
#define Un 64
#define UP1 65
#define Vn 1024
#define Dn 256
#define Hn 256
#define BLANKC 1023
#define NEGF (-1.0e30f)
#define CTCW 0.3f
#define R2E 1.4426950408889634f  // 1/ln2
#define LN2 0.6931471805599453f

typedef __attribute__((ext_vector_type(8))) short short8;
typedef __attribute__((ext_vector_type(4))) float f32x4;
typedef __attribute__((ext_vector_type(4))) unsigned int u32x4;

#define GLD_LDS16(gp, lp)                                                      \
  __builtin_amdgcn_global_load_lds(                                            \
      (const __attribute__((address_space(1))) void*)(gp),                     \
      (__attribute__((address_space(3))) void*)(lp), 16, 0, 0)

static __device__ __forceinline__ unsigned short f2bf(float f) {
  unsigned int u = __float_as_uint(f);
  u += 0x7FFFu + ((u >> 16) & 1u);
  return (unsigned short)(u >> 16);
}
static __device__ __forceinline__ unsigned int pack2bf(float a, float b) {
  return (unsigned int)f2bf(a) | ((unsigned int)f2bf(b) << 16);
}
static __device__ __forceinline__ float ftanh(float x) {
  float e = __expf(2.0f * x);
  return 1.0f - 2.0f / (e + 1.0f);
}
static __device__ __forceinline__ float ex2(float x) {
  return __builtin_amdgcn_exp2f(x);
}
static __device__ __forceinline__ float lg2(float x) {
  return __builtin_amdgcn_logf(x);
}
static __device__ __forceinline__ float laddexp2_(float x, float y) {
  float m = fmaxf(x, y);
  float d = y - x;
  return m + lg2(1.0f + ex2(-fabsf(d)));
}
static __device__ __forceinline__ float laddexp3_2(float a, float b, float c) {
  float m = fmaxf(fmaxf(a, b), c);
  return m + lg2(ex2(a - m) + ex2(b - m) + ex2(c - m));
}
// lane i <- lane i-1 (lane 0 gets 0; callers mask lane 0). DPP wave_shr:1.
static __device__ __forceinline__ float shfl_up1(float x) {
  int r = __builtin_amdgcn_update_dpp(0, __float_as_int(x), 0x138, 0xF, 0xF, false);
  return __int_as_float(r);
}

// ---------------------------------------------------------------------------
// K1 k_prep: W_out/W_ctc -> step-tiled bf16 layout Wt2[s=(c,ks)][sub][col][8k];
// W_enc/W_dec -> flat bf16 transpose. Zeroes d_out.
// ---------------------------------------------------------------------------
__global__ __launch_bounds__(256) void k_prep(
    const float* __restrict__ W_enc, const float* __restrict__ W_dec,
    const float* __restrict__ W_out, const float* __restrict__ W_ctc,
    unsigned short* __restrict__ Wt_enc, unsigned short* __restrict__ Wt_dec,
    unsigned short* __restrict__ Wt_out, unsigned short* __restrict__ Wt_ctc,
    float* __restrict__ out) {
  const int blk = blockIdx.x, tid = threadIdx.x;
  if (blk == 0 && tid == 0) out[0] = 0.0f;
  __shared__ float tilebuf[64][65];
  if (blk < 128) {
    const float* Wsrc = (blk < 64) ? W_out : W_ctc;
    unsigned short* Wd = (blk < 64) ? Wt_out : Wt_ctc;
    const int tt = blk & 63;
    const int k0 = (tt & 3) * 64, v0 = (tt >> 2) * 64;
#pragma unroll
    for (int rep = 0; rep < 16; ++rep) {
      int e = rep * 256 + tid;
      int rr = e >> 6, cc = e & 63;  // rr: k-off, cc: n-off
      tilebuf[rr][cc] = Wsrc[(k0 + rr) * 1024 + (v0 + cc)];
    }
    __syncthreads();
#pragma unroll
    for (int rep = 0; rep < 16; ++rep) {
      int e = rep * 256 + tid;
      int nn = e >> 6, kk = e & 63;
      int n = v0 + nn, k = k0 + kk;
      int c = n >> 8, col = n & 255;
      int ks = k >> 5, sub = (k >> 3) & 3, k7 = k & 7;
      Wd[(c * 8 + ks) * 8192 + sub * 2048 + col * 8 + k7] = f2bf(tilebuf[kk][nn]);
    }
  } else {
    const float* Wsrc = (blk < 144) ? W_enc : W_dec;
    unsigned short* Wd = (blk < 144) ? Wt_enc : Wt_dec;
    const int tt = (blk - 128) & 15;
    const int k0 = (tt & 3) * 64, v0 = (tt >> 2) * 64;
#pragma unroll
    for (int rep = 0; rep < 16; ++rep) {
      int e = rep * 256 + tid;
      int rr = e >> 6, cc = e & 63;
      tilebuf[rr][cc] = Wsrc[(k0 + rr) * 256 + (v0 + cc)];
    }
    __syncthreads();
#pragma unroll
    for (int rep = 0; rep < 16; ++rep) {
      int e = rep * 256 + tid;
      int rr = e >> 6, cc = e & 63;
      Wd[(v0 + rr) * 256 + (k0 + cc)] = f2bf(tilebuf[cc][rr]);
    }
  }
}

// ---------------------------------------------------------------------------
// K1b k_lin: enc_lin / dec_lin via MFMA (tiny; natural units out).
// ---------------------------------------------------------------------------
__global__ __launch_bounds__(256) void k_lin(
    const float* __restrict__ x_enc, const float* __restrict__ x_dec,
    const unsigned short* __restrict__ Wt_enc, const float* __restrict__ b_enc,
    const unsigned short* __restrict__ Wt_dec, const float* __restrict__ b_dec,
    float* __restrict__ enc_lin, float* __restrict__ dec_lin) {
  __shared__ __align__(16) char Asw[64 * 512];
  const int tid = threadIdx.x;
  const int w = tid >> 6, l = tid & 63;
  const int l15 = l & 15, l4 = l >> 4;
  const bool enc = blockIdx.x < 16;
  const int m0 = enc ? blockIdx.x * 64 : (blockIdx.x - 16) * 64;
  const int Mlim = enc ? 1024 : 260;
  const float* xp = enc ? x_enc : x_dec;
  const unsigned short* Wt = enc ? Wt_enc : Wt_dec;
  const float* bias = enc ? b_enc : b_dec;
  float* outp = enc ? enc_lin : dec_lin;

#pragma unroll
  for (int it = 0; it < 8; ++it) {
    int e = (it << 8) + tid;
    int i = e >> 5;
    int k0 = (e & 31) << 3;
    int r = m0 + i;
    if (r > Mlim - 1) r = Mlim - 1;
    const float* sp = xp + r * 256 + k0;
    f32x4 e0 = *(const f32x4*)sp;
    f32x4 e1 = *(const f32x4*)(sp + 4);
    u32x4 pv;
    pv[0] = pack2bf(e0[0], e0[1]);
    pv[1] = pack2bf(e0[2], e0[3]);
    pv[2] = pack2bf(e1[0], e1[1]);
    pv[3] = pack2bf(e1[2], e1[3]);
    int byt = (i << 9) + (k0 << 1);
    byt ^= (i & 7) << 4;
    *(u32x4*)(Asw + byt) = pv;
  }
  __syncthreads();

  const int nb = w * 64;
  f32x4 acc[4][4] = {};
#pragma unroll
  for (int ks = 0; ks < 8; ++ks) {
    int k = ks * 32 + l4 * 8;
    short8 af[4];
#pragma unroll
    for (int mt = 0; mt < 4; ++mt) {
      int i = mt * 16 + l15;
      int byt = (i << 9) + (k << 1);
      byt ^= (i & 7) << 4;
      af[mt] = *(const short8*)(Asw + byt);
    }
    short8 bfr[4];
#pragma unroll
    for (int nt = 0; nt < 4; ++nt) {
      int n = nb + nt * 16 + l15;
      bfr[nt] = *(const short8*)(Wt + n * 256 + k);
    }
#pragma unroll
    for (int mt = 0; mt < 4; ++mt)
#pragma unroll
      for (int nt = 0; nt < 4; ++nt)
        acc[mt][nt] = __builtin_amdgcn_mfma_f32_16x16x32_bf16(
            af[mt], bfr[nt], acc[mt][nt], 0, 0, 0);
  }
  float biasv[4];
#pragma unroll
  for (int nt = 0; nt < 4; ++nt) biasv[nt] = bias[nb + nt * 16 + l15];
#pragma unroll
  for (int mt = 0; mt < 4; ++mt)
#pragma unroll
    for (int rr = 0; rr < 4; ++rr) {
      int row = m0 + mt * 16 + l4 * 4 + rr;
      if (row < Mlim) {
#pragma unroll
        for (int nt = 0; nt < 4; ++nt)
          outp[row * 256 + nb + nt * 16 + l15] = acc[mt][nt][rr] + biasv[nt];
      }
    }
}

// ---------------------------------------------------------------------------
// K2 merged: blocks 0-7 = CTC head (128 frames); blocks 8-527 = joiner
// (128 rows). 8 waves = (wr,wc) 2x4. DEPTH-3 counted-vmcnt LDS pipeline:
// B staged per 16KB step via global_load_lds into a 3-buffer ring; per step
//   vmcnt(4) [stage(s) done, s+1/s+2 in flight] -> barrier -> ds_read+MFMA
//   -> barrier -> stage(s+3).
// Never vmcnt(0) in the main loop. Bias via LDS (lgkm-only, keeps the vmcnt
// hand-count clean). Base-2 folding throughout.
// ---------------------------------------------------------------------------
__global__ __launch_bounds__(512) void k_join2(
    const float* __restrict__ enc_lin, const float* __restrict__ dec_lin,
    const unsigned short* __restrict__ Wt_out, const float* __restrict__ b_out,
    const float* __restrict__ x_enc,
    const unsigned short* __restrict__ Wt_ctc, const float* __restrict__ b_ctc,
    const int* __restrict__ target,
    float* __restrict__ lp_blank, float* __restrict__ lp_label,
    float* __restrict__ ctc_blank, float* __restrict__ ctc_lse,
    float* __restrict__ ctc_lab) {
  __shared__ __align__(16) char Asw[128 * 512];   // 64KB A tile
  __shared__ __align__(16) char Bsw[3 * 16384];   // 48KB B ring
  __shared__ float s_bias[1024];                  // 4KB bias (base-2 scaled)
  __shared__ float s_psum[4][128];
  __shared__ float s_blank[128], s_label[128];
  __shared__ int s_tgt[128];

  const int tid = threadIdx.x;
  const int w = tid >> 6, l = tid & 63;
  const int wc = w & 3, wr = w >> 2;
  const int l15 = l & 15, l4 = l >> 4;
  const int bid = blockIdx.x;

  const bool joiner = bid >= 8;
  const unsigned short* Wt = joiner ? Wt_out : Wt_ctc;
  const float* biasp = joiner ? b_out : b_ctc;

  // stage step s (16KB linear chunk) into ring buffer `buf`; 2 loads/thread.
  auto stageB = [&](int s, int buf) {
#pragma unroll
    for (int r = 0; r < 2; ++r) {
      const unsigned short* src = Wt + s * 8192 + r * 4096 + tid * 8;
      GLD_LDS16(src, Bsw + buf * 16384 + r * 8192 + (w << 10));
    }
  };

  int b, r0 = 0, g0 = 0;
  if (joiner) {
    const int jbid = bid - 8;
    b = jbid / 130;
    r0 = (jbid % 130) * 128;
#pragma unroll
    for (int it = 0; it < 8; ++it) {
      int e = (it << 9) + tid;
      int i = e >> 5;  // row 0..127
      int k0 = (e & 31) << 3;
      int r = r0 + i;
      int t = r / 65;
      int u = r - t * 65;
      const float* ep = enc_lin + ((b * Tn + t) * Hn + k0);
      const float* dp = dec_lin + ((b * UP1 + u) * Hn + k0);
      f32x4 e0 = *(const f32x4*)ep;
      f32x4 e1 = *(const f32x4*)(ep + 4);
      f32x4 d0 = *(const f32x4*)dp;
      f32x4 d1 = *(const f32x4*)(dp + 4);
      u32x4 pv;
      pv[0] = pack2bf(ftanh(e0[0] + d0[0]) * R2E, ftanh(e0[1] + d0[1]) * R2E);
      pv[1] = pack2bf(ftanh(e0[2] + d0[2]) * R2E, ftanh(e0[3] + d0[3]) * R2E);
      pv[2] = pack2bf(ftanh(e1[0] + d1[0]) * R2E, ftanh(e1[1] + d1[1]) * R2E);
      pv[3] = pack2bf(ftanh(e1[2] + d1[2]) * R2E, ftanh(e1[3] + d1[3]) * R2E);
      int byt = (i << 9) + (k0 << 1);
      byt ^= (i & 7) << 4;
      *(u32x4*)(Asw + byt) = pv;
    }
    if (tid < 128) {
      int u = (r0 + tid) % 65;
      s_tgt[tid] = (u < Un) ? target[b * Un + u] : -1;
    }
  } else {
    g0 = bid * 128;
    b = g0 >> 8;
#pragma unroll
    for (int it = 0; it < 8; ++it) {
      int e = (it << 9) + tid;
      int i = e >> 5;
      int k0 = (e & 31) << 3;
      const float* sp = x_enc + (g0 + i) * Dn + k0;
      f32x4 e0 = *(const f32x4*)sp;
      f32x4 e1 = *(const f32x4*)(sp + 4);
      u32x4 pv;
      pv[0] = pack2bf(e0[0] * R2E, e0[1] * R2E);
      pv[1] = pack2bf(e0[2] * R2E, e0[3] * R2E);
      pv[2] = pack2bf(e1[0] * R2E, e1[1] * R2E);
      pv[3] = pack2bf(e1[2] * R2E, e1[3] * R2E);
      int byt = (i << 9) + (k0 << 1);
      byt ^= (i & 7) << 4;
      *(u32x4*)(Asw + byt) = pv;
    }
    if (tid < 64) s_tgt[tid] = target[b * Un + tid];
  }
  // bias -> LDS (lgkm path; no vmcnt pollution in the K-loop)
  for (int i = tid; i < 1024; i += 512) s_bias[i] = biasp[i] * R2E;
  __builtin_amdgcn_sched_barrier(0);
  stageB(0, 0);
  stageB(1, 1);
  stageB(2, 2);
  // Drain everything EXCEPT the 3 in-flight stages (6 loads); drain LDS writes.
  asm volatile("s_waitcnt vmcnt(6) lgkmcnt(0)" ::: "memory");
  __builtin_amdgcn_s_barrier();

  float ssum[16];
#pragma unroll
  for (int j = 0; j < 16; ++j) ssum[j] = 0.0f;

  int buf = 0;
#pragma unroll 1
  for (int c = 0; c < 4; ++c) {
    f32x4 acc[4][4] = {};
#pragma unroll
    for (int ks = 0; ks < 8; ++ks) {
      asm volatile("s_waitcnt vmcnt(4)" ::: "memory");  // stage(s) landed
      __builtin_amdgcn_s_barrier();
      __builtin_amdgcn_sched_barrier(0);
      const int bufb = buf * 16384;
      const int k = ks * 32 + l4 * 8;
      short8 af[4];
#pragma unroll
      for (int mt = 0; mt < 4; ++mt) {
        int i = wr * 64 + mt * 16 + l15;
        int byt = (i << 9) + (k << 1);
        byt ^= (i & 7) << 4;
        af[mt] = *(const short8*)(Asw + byt);
      }
      short8 bfr[4];
#pragma unroll
      for (int nt = 0; nt < 4; ++nt) {
        int byt = bufb + l4 * 4096 + ((wc * 64 + nt * 16 + l15) << 4);
        bfr[nt] = *(const short8*)(Bsw + byt);
      }
#pragma unroll
      for (int mt = 0; mt < 4; ++mt)
#pragma unroll
        for (int nt = 0; nt < 4; ++nt)
          acc[mt][nt] = __builtin_amdgcn_mfma_f32_16x16x32_bf16(
              af[mt], bfr[nt], acc[mt][nt], 0, 0, 0);
      __builtin_amdgcn_sched_barrier(0);
      __builtin_amdgcn_s_barrier();  // all waves consumed buf
      const int s = c * 8 + ks;
      const int nst = (s + 3 < 32) ? s + 3 : 31;
      stageB(nst, buf);  // refill the buffer just consumed
      __builtin_amdgcn_sched_barrier(0);
      buf = (buf == 2) ? 0 : buf + 1;
    }
    const int nb = c * 256 + wc * 64;
    float biasv[4];
#pragma unroll
    for (int nt = 0; nt < 4; ++nt) biasv[nt] = s_bias[nb + nt * 16 + l15];
#pragma unroll
    for (int mt = 0; mt < 4; ++mt)
#pragma unroll
      for (int nt = 0; nt < 4; ++nt)
#pragma unroll
        for (int rr = 0; rr < 4; ++rr) acc[mt][nt][rr] += biasv[nt];

    if (joiner) {
      if (c == 3 && wc == 3 && l15 == 15) {
#pragma unroll
        for (int mt = 0; mt < 4; ++mt)
#pragma unroll
          for (int rr = 0; rr < 4; ++rr)
            s_blank[wr * 64 + mt * 16 + l4 * 4 + rr] = acc[mt][3][rr];
      }
#pragma unroll
      for (int mt = 0; mt < 4; ++mt)
#pragma unroll
        for (int rr = 0; rr < 4; ++rr) {
          int row = wr * 64 + mt * 16 + l4 * 4 + rr;
          int tg = s_tgt[row];
          if ((tg >> 8) == c && ((tg >> 6) & 3) == wc && (tg & 15) == l15) {
            int ntv = (tg >> 4) & 3;
            float v01 = (ntv & 1) ? acc[mt][1][rr] : acc[mt][0][rr];
            float v23 = (ntv & 1) ? acc[mt][3][rr] : acc[mt][2][rr];
            s_label[row] = (ntv & 2) ? v23 : v01;
          }
        }
    } else {
      if (c == 3 && wc == 3 && l15 == 15) {
#pragma unroll
        for (int mt = 0; mt < 4; ++mt)
#pragma unroll
          for (int rr = 0; rr < 4; ++rr)
            s_blank[wr * 64 + mt * 16 + l4 * 4 + rr] = acc[mt][3][rr];
      }
#pragma unroll 1
      for (int u = 0; u < 64; ++u) {
        int tgu = s_tgt[u];
        if ((tgu >> 8) == c && ((tgu >> 6) & 3) == wc) {
          int ntv = (tgu >> 4) & 3;
          if ((tgu & 15) == l15) {
#pragma unroll
            for (int mt = 0; mt < 4; ++mt)
#pragma unroll
              for (int rr = 0; rr < 4; ++rr) {
                float v01 = (ntv & 1) ? acc[mt][1][rr] : acc[mt][0][rr];
                float v23 = (ntv & 1) ? acc[mt][3][rr] : acc[mt][2][rr];
                float v = (ntv & 2) ? v23 : v01;
                ctc_lab[(g0 + wr * 64 + mt * 16 + l4 * 4 + rr) * 64 + u] = v;
              }
          }
        }
      }
      // stores only make subsequent vmcnt(4) waits conservative (safe).
    }
#pragma unroll
    for (int mt = 0; mt < 4; ++mt)
#pragma unroll
      for (int rr = 0; rr < 4; ++rr)
        ssum[mt * 4 + rr] += ex2(acc[mt][0][rr]) + ex2(acc[mt][1][rr]) +
                             ex2(acc[mt][2][rr]) + ex2(acc[mt][3][rr]);
  }

#pragma unroll
  for (int ms = 1; ms < 16; ms <<= 1)
#pragma unroll
    for (int j = 0; j < 16; ++j) ssum[j] += __shfl_xor(ssum[j], ms, 64);
  if (l15 == 0) {
#pragma unroll
    for (int j = 0; j < 16; ++j)
      s_psum[wc][wr * 64 + (j >> 2) * 16 + l4 * 4 + (j & 3)] = ssum[j];
  }
  __syncthreads();  // also drains the tail dummy stages

  if (tid < 128) {
    float tot = s_psum[0][tid] + s_psum[1][tid] + s_psum[2][tid] + s_psum[3][tid];
    float lse = lg2(tot);  // base-2 LSE
    if (joiner) {
      int r = r0 + tid;
      int t = r / 65;
      int u = r - t * 65;
      lp_blank[(b * Tn + t) * UP1 + u] = s_blank[tid] - lse;   // base-2 units
      if (u < Un) lp_label[(b * Tn + t) * Un + u] = s_label[tid] - lse;
    } else {
      ctc_blank[g0 + tid] = s_blank[tid] - lse;                // base-2 units
      ctc_lse[g0 + tid] = lse;
    }
  }
}

// ---------------------------------------------------------------------------
// K3 k_dp: blocks 0-3 RNNT anti-diagonal DP; blocks 4-7 CTC DP.
// Base-2 inputs; native v_exp/v_log chain; *LN2 once at the atomicAdd.
// EARLY-EXIT bounds: RNNT runs only to dstar, CTC to ft-1 (padded states
// provably frozen/unused). 8-step register prefetch with sched_barriers.
// ---------------------------------------------------------------------------
__global__ __launch_bounds__(256) void k_dp(
    const float* __restrict__ lp_blank, const float* __restrict__ lp_label,
    const float* __restrict__ ctc_blank, const float* __restrict__ ctc_lse,
    const float* __restrict__ ctc_lab,
    const int* __restrict__ target,
    const int* __restrict__ flen, const int* __restrict__ tlen,
    float* __restrict__ out) {
  __shared__ float sA[256 * 66];             // RNNT lp_blank2[t][u], stride 66
  __shared__ __align__(16) float sB[16384];  // RNNT lp_label2 ; CTC raw2
  __shared__ float sC[256], sD[256];         // CTC blank2, lse2
  __shared__ float cT[129];
  const int tid = threadIdx.x;
  const int l = tid & 63;

  if (blockIdx.x < 4) {
    const int b = blockIdx.x;
    for (int i = tid; i < 16640; i += 256) {
      int r = i / 65, cidx = i - r * 65;
      sA[r * 66 + cidx] = lp_blank[b * 16640 + i];
    }
    {
      const f32x4* g2 = (const f32x4*)(lp_label + b * 16384);
      f32x4* s2 = (f32x4*)sB;
      for (int i = tid; i < 4096; i += 256) s2[i] = g2[i];
    }
    __syncthreads();
    if (tid < 64) {
      const int ft = flen[b], tl = tlen[b];
      const int dstar = ft - 1 + tl;
      const bool isown = (l == tl);
      const bool is64 = (tl == 64) && (l == 63);
      const int lc = (l >= 1) ? l - 1 : 0;

#define RLOAD(D0, VB, VL, VB64, VL64)                                          \
  _Pragma("unroll") for (int j = 0; j < 8; ++j) {                              \
    const int d_ = (D0) + j;                                                   \
    const int t_ = d_ - l;                                                     \
    const int tbc_ = (t_ < 1) ? 1 : (t_ > 255 ? 255 : t_);                     \
    const int tcc_ = (t_ < 0) ? 0 : (t_ > 255 ? 255 : t_);                     \
    VB[j] = sA[(tbc_ - 1) * 66 + l];                                           \
    VL[j] = (l == 0) ? NEGF : sB[tcc_ * 64 + lc];                              \
    const int t64_ = d_ - 64;                                                  \
    const int t64b_ = (t64_ < 1) ? 1 : (t64_ > 255 ? 255 : t64_);              \
    const int t64c_ = (t64_ < 0) ? 0 : (t64_ > 255 ? 255 : t64_);              \
    VB64[j] = sA[(t64b_ - 1) * 66 + 64];                                       \
    VL64[j] = sB[t64c_ * 64 + 63];                                             \
  }

      float cvb[8], cvl[8], cvb64[8], cvl64[8];
      RLOAD(1, cvb, cvl, cvb64, cvl64);
      float a = (l == 0) ? 0.0f : NEGF;
      float a64 = NEGF, cap = NEGF;
      for (int d0 = 1; d0 <= dstar; d0 += 8) {  // early exit past dstar
        float nvb[8], nvl[8], nvb64[8], nvl64[8];
        RLOAD(d0 + 8, nvb, nvl, nvb64, nvl64);  // prefetch next block
        __builtin_amdgcn_sched_barrier(0);
#pragma unroll
        for (int j = 0; j < 8; ++j) {  // base-2 chain, no range predication
          const int d = d0 + j;
          float aleft = shfl_up1(a);
          float x = a + cvb[j];
          float y = aleft + cvl[j];            // lane 0: cvl = NEGF
          float nw = laddexp2_(x, y);
          float nw64 = laddexp2_(a64 + cvb64[j], a + cvl64[j]);  // old a
          a = nw;
          a64 = (l == 63) ? nw64 : a64;
          bool hit = (d == dstar);
          cap = (hit && isown) ? a : cap;
          cap = (hit && is64) ? a64 : cap;
        }
        __builtin_amdgcn_sched_barrier(0);
#pragma unroll
        for (int j = 0; j < 8; ++j) {
          cvb[j] = nvb[j];
          cvl[j] = nvl[j];
          cvb64[j] = nvb64[j];
          cvl64[j] = nvl64[j];
        }
      }
#undef RLOAD
      bool owner = (tl < 64) ? isown : (l == 63);
      if (owner)
        atomicAdd(out, -0.25f * LN2 * (cap + sA[(ft - 1) * 66 + tl]));
    }
  } else {
    const int b = blockIdx.x - 4;
    {
      const f32x4* g2 = (const f32x4*)(ctc_lab + b * 16384);
      f32x4* s2 = (f32x4*)sB;
      for (int i = tid; i < 4096; i += 256) s2[i] = g2[i];
      sC[tid] = ctc_blank[b * 256 + tid];
      sD[tid] = ctc_lse[b * 256 + tid];
    }
    __syncthreads();
    if (tid < 64) {
      const int ft = flen[b], tl = tlen[b];
      const int tg = target[b * Un + l];
      const int tgp = (l >= 1) ? target[b * Un + l - 1] : -1;
      const bool skip1 = (l >= 1) && (tg != tgp);

#define CLOAD(T0, EB, E1)                                                      \
  _Pragma("unroll") for (int j = 0; j < 8; ++j) {                              \
    const int tc_ = ((T0) + j > 255) ? 255 : (T0) + j;                         \
    EB[j] = sC[tc_];                                                           \
    E1[j] = sB[tc_ * 64 + l] - sD[tc_];                                        \
  }

      float ceb[8], ce1[8];
      CLOAD(1, ceb, ce1);
      float a0 = (l == 0) ? sC[0] : NEGF;
      float a1 = (l == 0) ? (sB[0] - sD[0]) : NEGF;
      float a2 = NEGF;
      for (int t0 = 1; t0 < ft; t0 += 8) {  // early exit at ft (frozen past)
        float neb[8], ne1[8];
        CLOAD(t0 + 8, neb, ne1);
        __builtin_amdgcn_sched_barrier(0);
#pragma unroll
        for (int j = 0; j < 8; ++j) {
          const int t = t0 + j;
          float pm1 = shfl_up1(a1);
          pm1 = (l == 0) ? NEGF : pm1;
          float n0 = ceb[j] + laddexp2_(a0, pm1);
          float n1 = ce1[j] + laddexp3_2(a1, a0, skip1 ? pm1 : NEGF);
          float n2 = ceb[j] + laddexp2_(a2, a1);
          bool run = (t < ft);
          a0 = run ? n0 : a0;
          a1 = run ? n1 : a1;
          a2 = (run && (l == 63)) ? n2 : a2;
        }
        __builtin_amdgcn_sched_barrier(0);
#pragma unroll
        for (int j = 0; j < 8; ++j) {
          ceb[j] = neb[j];
          ce1[j] = ne1[j];
        }
      }
#undef CLOAD
      cT[2 * l] = a0;
      cT[2 * l + 1] = a1;
      if (l == 63) cT[128] = a2;
      __builtin_amdgcn_s_waitcnt(0);  // intra-wave lgkm drain before readback
      if (l == 0) {
        int sl = 2 * tl;
        float ll = laddexp2_(cT[sl], cT[sl - 1]);  // base-2 units
        float lb = (ll < NEGF * 0.7f) ? 0.0f : -ll;
        atomicAdd(out, CTCW * 0.25f * LN2 * lb);
      }
    }
  }
}

// ---------------------------------------------------------------------------
extern "C" void kernel_launch(void* const* d_in, const int* in_sizes, int n_in,
                              void* d_out, int out_size, void* d_ws, size_t ws_size,
                              hipStream_t stream) {
  (void)in_sizes; (void)n_in; (void)out_size; (void)ws_size;
  const float* x_enc = (const float*)d_in[0];
  const float* x_dec = (const float*)d_in[1];
  const float* W_enc = (const float*)d_in[2];
  const float* b_enc = (const float*)d_in[3];
  const float* W_dec = (const float*)d_in[4];
  const float* b_dec = (const float*)d_in[5];
  const float* W_out = (const float*)d_in[6];
  const float* b_out = (const float*)d_in[7];
  const float* W_ctc = (const float*)d_in[8];
  const float* b_ctc = (const float*)d_in[9];
  const int* target = (const int*)d_in[10];
  const int* flen = (const int*)d_in[11];
  const int* tlen = (const int*)d_in[12];

  float* ws = (float*)d_ws;
  float* enc_lin = ws;                    // 262144
  float* dec_lin = ws + 262144;           // 66560
  float* lp_blank = ws + 328704;          // 66560
  float* lp_label = ws + 395264;          // 65536
  float* ctc_blank = ws + 460800;         // 1024
  float* ctc_lse = ws + 461824;           // 1024
  float* ctc_lab = ws + 462848;           // 65536
  unsigned short* Wt_out = (unsigned short*)(ws + 528384);  // 262144 bf16 (tiled)
  unsigned short* Wt_ctc = Wt_out + 262144;                 // 262144 bf16 (tiled)
  unsigned short* Wt_enc = (unsigned short*)lp_blank;       // 65536 bf16
  unsigned short* Wt_dec = (unsigned short*)lp_label;       // 65536 bf16
  float* out = (float*)d_out;

  k_prep<<<dim3(160), dim3(256), 0, stream>>>(
      W_enc, W_dec, W_out, W_ctc, Wt_enc, Wt_dec, Wt_out, Wt_ctc, out);
  k_lin<<<dim3(21), dim3(256), 0, stream>>>(
      x_enc, x_dec, Wt_enc, b_enc, Wt_dec, b_dec, enc_lin, dec_lin);
  k_join2<<<dim3(528), dim3(512), 0, stream>>>(
      enc_lin, dec_lin, Wt_out, b_out, x_enc, Wt_ctc, b_ctc, target,
      lp_blank, lp_label, ctc_blank, ctc_lse, ctc_lab);
  k_dp<<<dim3(8), dim3(64 * 4), 0, stream>>>(
      lp_blank, lp_label, ctc_blank, ctc_lse, ctc_lab, target, flen, tlen, out);
}

// Round 16
// 121.864 us; speedup vs baseline: 1.2970x; 1.2970x over previous
//
#include <hip/hip_runtime.h>
#include <hip/hip_bf16.h>

#define Bn 4
#define Tn 256
#define Un 64
#define UP1 65
#define Vn 1024
#define Dn 256
#define Hn 256
#define BLANKC 1023
#define NEGF (-1.0e30f)
#define CTCW 0.3f
#define R2E 1.4426950408889634f  // 1/ln2
#define LN2 0.6931471805599453f

typedef __attribute__((ext_vector_type(8))) short short8;
typedef __attribute__((ext_vector_type(4))) float f32x4;
typedef __attribute__((ext_vector_type(4))) unsigned int u32x4;

static __device__ __forceinline__ unsigned short f2bf(float f) {
  unsigned int u = __float_as_uint(f);
  u += 0x7FFFu + ((u >> 16) & 1u);
  return (unsigned short)(u >> 16);
}
static __device__ __forceinline__ unsigned int pack2bf(float a, float b) {
  return (unsigned int)f2bf(a) | ((unsigned int)f2bf(b) << 16);
}
static __device__ __forceinline__ float ftanh(float x) {
  float e = __expf(2.0f * x);
  return 1.0f - 2.0f / (e + 1.0f);
}
static __device__ __forceinline__ float ex2(float x) {
  return __builtin_amdgcn_exp2f(x);
}
static __device__ __forceinline__ float lg2(float x) {
  return __builtin_amdgcn_logf(x);
}
// base-2 logaddexp; safe for +-1e30 garbage magnitudes (max-form).
static __device__ __forceinline__ float laddexp2_(float x, float y) {
  float m = fmaxf(x, y);
  float d = y - x;
  return m + lg2(1.0f + ex2(-fabsf(d)));
}
static __device__ __forceinline__ float laddexp3_2(float a, float b, float c) {
  float m = fmaxf(fmaxf(a, b), c);
  return m + lg2(ex2(a - m) + ex2(b - m) + ex2(c - m));
}
// lane i <- lane i-1 (lane 0 gets 0; callers mask lane 0). DPP wave_shr:1.
static __device__ __forceinline__ float shfl_up1(float x) {
  int r = __builtin_amdgcn_update_dpp(0, __float_as_int(x), 0x138, 0xF, 0xF, false);
  return __int_as_float(r);
}

// ---------------------------------------------------------------------------
// K1 k_prep: W_out/W_ctc -> step-tiled bf16 layout Wt2[s=(c,ks)][sub][col][8k];
// W_enc/W_dec -> flat bf16 transpose. Zeroes d_out.
// ---------------------------------------------------------------------------
__global__ __launch_bounds__(256) void k_prep(
    const float* __restrict__ W_enc, const float* __restrict__ W_dec,
    const float* __restrict__ W_out, const float* __restrict__ W_ctc,
    unsigned short* __restrict__ Wt_enc, unsigned short* __restrict__ Wt_dec,
    unsigned short* __restrict__ Wt_out, unsigned short* __restrict__ Wt_ctc,
    float* __restrict__ out) {
  const int blk = blockIdx.x, tid = threadIdx.x;
  if (blk == 0 && tid == 0) out[0] = 0.0f;
  __shared__ float tilebuf[64][65];
  if (blk < 128) {
    const float* Wsrc = (blk < 64) ? W_out : W_ctc;
    unsigned short* Wd = (blk < 64) ? Wt_out : Wt_ctc;
    const int tt = blk & 63;
    const int k0 = (tt & 3) * 64, v0 = (tt >> 2) * 64;
#pragma unroll
    for (int rep = 0; rep < 16; ++rep) {
      int e = rep * 256 + tid;
      int rr = e >> 6, cc = e & 63;  // rr: k-off, cc: n-off
      tilebuf[rr][cc] = Wsrc[(k0 + rr) * 1024 + (v0 + cc)];
    }
    __syncthreads();
#pragma unroll
    for (int rep = 0; rep < 16; ++rep) {
      int e = rep * 256 + tid;
      int nn = e >> 6, kk = e & 63;
      int n = v0 + nn, k = k0 + kk;
      int c = n >> 8, col = n & 255;
      int ks = k >> 5, sub = (k >> 3) & 3, k7 = k & 7;
      Wd[(c * 8 + ks) * 8192 + sub * 2048 + col * 8 + k7] = f2bf(tilebuf[kk][nn]);
    }
  } else {
    const float* Wsrc = (blk < 144) ? W_enc : W_dec;
    unsigned short* Wd = (blk < 144) ? Wt_enc : Wt_dec;
    const int tt = (blk - 128) & 15;
    const int k0 = (tt & 3) * 64, v0 = (tt >> 2) * 64;
#pragma unroll
    for (int rep = 0; rep < 16; ++rep) {
      int e = rep * 256 + tid;
      int rr = e >> 6, cc = e & 63;
      tilebuf[rr][cc] = Wsrc[(k0 + rr) * 256 + (v0 + cc)];
    }
    __syncthreads();
#pragma unroll
    for (int rep = 0; rep < 16; ++rep) {
      int e = rep * 256 + tid;
      int rr = e >> 6, cc = e & 63;
      Wd[(v0 + rr) * 256 + (k0 + cc)] = f2bf(tilebuf[cc][rr]);
    }
  }
}

// ---------------------------------------------------------------------------
// K1b k_lin: enc_lin / dec_lin via MFMA (tiny; natural units out).
// ---------------------------------------------------------------------------
__global__ __launch_bounds__(256) void k_lin(
    const float* __restrict__ x_enc, const float* __restrict__ x_dec,
    const unsigned short* __restrict__ Wt_enc, const float* __restrict__ b_enc,
    const unsigned short* __restrict__ Wt_dec, const float* __restrict__ b_dec,
    float* __restrict__ enc_lin, float* __restrict__ dec_lin) {
  __shared__ __align__(16) char Asw[64 * 512];
  const int tid = threadIdx.x;
  const int w = tid >> 6, l = tid & 63;
  const int l15 = l & 15, l4 = l >> 4;
  const bool enc = blockIdx.x < 16;
  const int m0 = enc ? blockIdx.x * 64 : (blockIdx.x - 16) * 64;
  const int Mlim = enc ? 1024 : 260;
  const float* xp = enc ? x_enc : x_dec;
  const unsigned short* Wt = enc ? Wt_enc : Wt_dec;
  const float* bias = enc ? b_enc : b_dec;
  float* outp = enc ? enc_lin : dec_lin;

#pragma unroll
  for (int it = 0; it < 8; ++it) {
    int e = (it << 8) + tid;
    int i = e >> 5;
    int k0 = (e & 31) << 3;
    int r = m0 + i;
    if (r > Mlim - 1) r = Mlim - 1;
    const float* sp = xp + r * 256 + k0;
    f32x4 e0 = *(const f32x4*)sp;
    f32x4 e1 = *(const f32x4*)(sp + 4);
    u32x4 pv;
    pv[0] = pack2bf(e0[0], e0[1]);
    pv[1] = pack2bf(e0[2], e0[3]);
    pv[2] = pack2bf(e1[0], e1[1]);
    pv[3] = pack2bf(e1[2], e1[3]);
    int byt = (i << 9) + (k0 << 1);
    byt ^= (i & 7) << 4;
    *(u32x4*)(Asw + byt) = pv;
  }
  __syncthreads();

  const int nb = w * 64;
  f32x4 acc[4][4] = {};
#pragma unroll
  for (int ks = 0; ks < 8; ++ks) {
    int k = ks * 32 + l4 * 8;
    short8 af[4];
#pragma unroll
    for (int mt = 0; mt < 4; ++mt) {
      int i = mt * 16 + l15;
      int byt = (i << 9) + (k << 1);
      byt ^= (i & 7) << 4;
      af[mt] = *(const short8*)(Asw + byt);
    }
    short8 bfr[4];
#pragma unroll
    for (int nt = 0; nt < 4; ++nt) {
      int n = nb + nt * 16 + l15;
      bfr[nt] = *(const short8*)(Wt + n * 256 + k);
    }
#pragma unroll
    for (int mt = 0; mt < 4; ++mt)
#pragma unroll
      for (int nt = 0; nt < 4; ++nt)
        acc[mt][nt] = __builtin_amdgcn_mfma_f32_16x16x32_bf16(
            af[mt], bfr[nt], acc[mt][nt], 0, 0, 0);
  }
  float biasv[4];
#pragma unroll
  for (int nt = 0; nt < 4; ++nt) biasv[nt] = bias[nb + nt * 16 + l15];
#pragma unroll
  for (int mt = 0; mt < 4; ++mt)
#pragma unroll
    for (int rr = 0; rr < 4; ++rr) {
      int row = m0 + mt * 16 + l4 * 4 + rr;
      if (row < Mlim) {
#pragma unroll
        for (int nt = 0; nt < 4; ++nt)
          outp[row * 256 + nb + nt * 16 + l15] = acc[mt][nt][rr] + biasv[nt];
      }
    }
}

// ---------------------------------------------------------------------------
// K2 merged: blocks 0-15 = CTC head; blocks 16-1055 = joiner.
// Best-measured structure (Round-13 bench: join 70.6us): 64-row blocks,
// DEPTH-2 even/odd register B pipeline (VGPR 120, 4 blocks/CU, barrier-free
// K-loop) + per-block chunk rotation + base-2 folding.
// ---------------------------------------------------------------------------
__global__ __launch_bounds__(256) void k_join2(
    const float* __restrict__ enc_lin, const float* __restrict__ dec_lin,
    const unsigned short* __restrict__ Wt_out, const float* __restrict__ b_out,
    const float* __restrict__ x_enc,
    const unsigned short* __restrict__ Wt_ctc, const float* __restrict__ b_ctc,
    const int* __restrict__ target,
    float* __restrict__ lp_blank, float* __restrict__ lp_label,
    float* __restrict__ ctc_blank, float* __restrict__ ctc_lse,
    float* __restrict__ ctc_lab) {
  __shared__ __align__(16) char Asw[64 * 512];    // 32KB A tile
  __shared__ float s_psum[4][64];
  __shared__ float s_blank[64], s_label[64];
  __shared__ int s_tgt[64];

  const int tid = threadIdx.x;
  const int w = tid >> 6, l = tid & 63;
  const int l15 = l & 15, l4 = l >> 4;
  const int bid = blockIdx.x;

  const bool joiner = bid >= 16;
  const unsigned short* Wt = joiner ? Wt_out : Wt_ctc;
  const float* bias = joiner ? b_out : b_ctc;

  // B base: step s, col = w*64 + nt*16 + l15, sub = l4.
  const unsigned short* tb = Wt + l4 * 2048 + (w * 64 + l15) * 8;

  short8 bE[4], bO[4];
#define LOADB(REG, S)                                                          \
  {                                                                            \
    const unsigned short* p_ = tb + (S)*8192;                                  \
    _Pragma("unroll") for (int nt = 0; nt < 4; ++nt)                           \
        REG[nt] = *(const short8*)(p_ + nt * 128);                             \
  }
  {
    const int sc0 = (bid & 3) * 8;
    LOADB(bE, sc0 + 0)
    LOADB(bO, sc0 + 1)
  }

  int b, r0 = 0, g0 = 0;
  if (joiner) {
    const int jbid = bid - 16;
    b = jbid / 260;
    r0 = (jbid % 260) * 64;
#pragma unroll
    for (int it = 0; it < 8; ++it) {
      int e = (it << 8) + tid;
      int i = e >> 5;
      int k0 = (e & 31) << 3;
      int r = r0 + i;
      int t = r / 65;
      int u = r - t * 65;
      const float* ep = enc_lin + ((b * Tn + t) * Hn + k0);
      const float* dp = dec_lin + ((b * UP1 + u) * Hn + k0);
      f32x4 e0 = *(const f32x4*)ep;
      f32x4 e1 = *(const f32x4*)(ep + 4);
      f32x4 d0 = *(const f32x4*)dp;
      f32x4 d1 = *(const f32x4*)(dp + 4);
      u32x4 pv;
      pv[0] = pack2bf(ftanh(e0[0] + d0[0]) * R2E, ftanh(e0[1] + d0[1]) * R2E);
      pv[1] = pack2bf(ftanh(e0[2] + d0[2]) * R2E, ftanh(e0[3] + d0[3]) * R2E);
      pv[2] = pack2bf(ftanh(e1[0] + d1[0]) * R2E, ftanh(e1[1] + d1[1]) * R2E);
      pv[3] = pack2bf(ftanh(e1[2] + d1[2]) * R2E, ftanh(e1[3] + d1[3]) * R2E);
      int byt = (i << 9) + (k0 << 1);
      byt ^= (i & 7) << 4;
      *(u32x4*)(Asw + byt) = pv;
    }
    if (tid < 64) {
      int u = (r0 + tid) % 65;
      s_tgt[tid] = (u < Un) ? target[b * Un + u] : -1;
    }
  } else {
    g0 = bid * 64;
    b = g0 >> 8;
#pragma unroll
    for (int it = 0; it < 8; ++it) {
      int e = (it << 8) + tid;
      int i = e >> 5;
      int k0 = (e & 31) << 3;
      const float* sp = x_enc + (g0 + i) * Dn + k0;
      f32x4 e0 = *(const f32x4*)sp;
      f32x4 e1 = *(const f32x4*)(sp + 4);
      u32x4 pv;
      pv[0] = pack2bf(e0[0] * R2E, e0[1] * R2E);
      pv[1] = pack2bf(e0[2] * R2E, e0[3] * R2E);
      pv[2] = pack2bf(e1[0] * R2E, e1[1] * R2E);
      pv[3] = pack2bf(e1[2] * R2E, e1[3] * R2E);
      int byt = (i << 9) + (k0 << 1);
      byt ^= (i & 7) << 4;
      *(u32x4*)(Asw + byt) = pv;
    }
    if (tid < 64) s_tgt[tid] = target[b * Un + tid];
  }
  __syncthreads();  // A tile + s_tgt ready; the ONLY pre-epilogue barrier

  float ssum[16];
#pragma unroll
  for (int j = 0; j < 16; ++j) ssum[j] = 0.0f;

#define MFMASTEP(REG, KS)                                                      \
  {                                                                            \
    const int k_ = (KS)*32 + l4 * 8;                                           \
    _Pragma("unroll") for (int mt = 0; mt < 4; ++mt) {                         \
      int i_ = mt * 16 + l15;                                                  \
      int byt_ = ((i_ << 9) + (k_ << 1)) ^ ((i_ & 7) << 4);                    \
      short8 af_ = *(const short8*)(Asw + byt_);                               \
      _Pragma("unroll") for (int nt = 0; nt < 4; ++nt)                         \
          acc[mt][nt] = __builtin_amdgcn_mfma_f32_16x16x32_bf16(               \
              af_, REG[nt], acc[mt][nt], 0, 0, 0);                             \
    }                                                                          \
  }
#define SB __builtin_amdgcn_sched_barrier(0)

#pragma unroll 1
  for (int cr = 0; cr < 4; ++cr) {
    const int cc = (cr + bid) & 3;             // rotated chunk id (uniform)
    const int sc = cc * 8;
    const int scn = ((cr + 1 + bid) & 3) * 8;  // next chunk's step base
    f32x4 acc[4][4] = {};
    MFMASTEP(bE, 0) LOADB(bE, sc + 2) SB;
    MFMASTEP(bO, 1) LOADB(bO, sc + 3) SB;
    MFMASTEP(bE, 2) LOADB(bE, sc + 4) SB;
    MFMASTEP(bO, 3) LOADB(bO, sc + 5) SB;
    MFMASTEP(bE, 4) LOADB(bE, sc + 6) SB;
    MFMASTEP(bO, 5) LOADB(bO, sc + 7) SB;
    MFMASTEP(bE, 6) LOADB(bE, (cr < 3) ? scn + 0 : sc + 6) SB;
    MFMASTEP(bO, 7) LOADB(bO, (cr < 3) ? scn + 1 : sc + 7) SB;

    const int nb = cc * 256 + w * 64;
    float biasv[4];
#pragma unroll
    for (int nt = 0; nt < 4; ++nt) biasv[nt] = bias[nb + nt * 16 + l15] * R2E;
#pragma unroll
    for (int mt = 0; mt < 4; ++mt)
#pragma unroll
      for (int nt = 0; nt < 4; ++nt)
#pragma unroll
        for (int rr = 0; rr < 4; ++rr) acc[mt][nt][rr] += biasv[nt];

    if (joiner) {
      if (cc == 3 && w == 3 && l15 == 15) {
#pragma unroll
        for (int mt = 0; mt < 4; ++mt)
#pragma unroll
          for (int rr = 0; rr < 4; ++rr)
            s_blank[mt * 16 + l4 * 4 + rr] = acc[mt][3][rr];
      }
#pragma unroll
      for (int mt = 0; mt < 4; ++mt)
#pragma unroll
        for (int rr = 0; rr < 4; ++rr) {
          int row = mt * 16 + l4 * 4 + rr;
          int tg = s_tgt[row];
          if ((tg >> 8) == cc && ((tg >> 6) & 3) == w && (tg & 15) == l15) {
            int ntv = (tg >> 4) & 3;
            float v01 = (ntv & 1) ? acc[mt][1][rr] : acc[mt][0][rr];
            float v23 = (ntv & 1) ? acc[mt][3][rr] : acc[mt][2][rr];
            s_label[row] = (ntv & 2) ? v23 : v01;
          }
        }
    } else {
      if (cc == 3 && w == 3 && l15 == 15) {
#pragma unroll
        for (int mt = 0; mt < 4; ++mt)
#pragma unroll
          for (int rr = 0; rr < 4; ++rr)
            s_blank[mt * 16 + l4 * 4 + rr] = acc[mt][3][rr];
      }
#pragma unroll 1
      for (int u = 0; u < 64; ++u) {
        int tgu = s_tgt[u];
        if ((tgu >> 8) == cc && ((tgu >> 6) & 3) == w) {
          int ntv = (tgu >> 4) & 3;
          if ((tgu & 15) == l15) {
#pragma unroll
            for (int mt = 0; mt < 4; ++mt)
#pragma unroll
              for (int rr = 0; rr < 4; ++rr) {
                float v01 = (ntv & 1) ? acc[mt][1][rr] : acc[mt][0][rr];
                float v23 = (ntv & 1) ? acc[mt][3][rr] : acc[mt][2][rr];
                float v = (ntv & 2) ? v23 : v01;
                ctc_lab[(g0 + mt * 16 + l4 * 4 + rr) * 64 + u] = v;
              }
          }
        }
      }
    }
    // base-2 exp-sum: acc already in log2 units, raw v_exp (no mul)
#pragma unroll
    for (int mt = 0; mt < 4; ++mt)
#pragma unroll
      for (int rr = 0; rr < 4; ++rr)
        ssum[mt * 4 + rr] += ex2(acc[mt][0][rr]) + ex2(acc[mt][1][rr]) +
                             ex2(acc[mt][2][rr]) + ex2(acc[mt][3][rr]);
  }
#undef MFMASTEP
#undef LOADB
#undef SB

#pragma unroll
  for (int ms = 1; ms < 16; ms <<= 1)
#pragma unroll
    for (int j = 0; j < 16; ++j) ssum[j] += __shfl_xor(ssum[j], ms, 64);
  if (l15 == 0) {
#pragma unroll
    for (int j = 0; j < 16; ++j)
      s_psum[w][(j >> 2) * 16 + l4 * 4 + (j & 3)] = ssum[j];
  }
  __syncthreads();

  if (tid < 64) {
    float tot = s_psum[0][tid] + s_psum[1][tid] + s_psum[2][tid] + s_psum[3][tid];
    float lse = lg2(tot);  // base-2 LSE
    if (joiner) {
      int r = r0 + tid;
      int t = r / 65;
      int u = r - t * 65;
      lp_blank[(b * Tn + t) * UP1 + u] = s_blank[tid] - lse;   // base-2 units
      if (u < Un) lp_label[(b * Tn + t) * Un + u] = s_label[tid] - lse;
    } else {
      ctc_blank[g0 + tid] = s_blank[tid] - lse;                // base-2 units
      ctc_lse[g0 + tid] = lse;
    }
  }
}

// ---------------------------------------------------------------------------
// K3 k_dp: blocks 0-3 RNNT anti-diagonal DP; blocks 4-7 CTC DP.
// Base-2 inputs; native v_exp/v_log chain; *LN2 once at the atomicAdd.
// EARLY-EXIT bounds (new this round): RNNT runs only to dstar (cap captured
// at d==dstar; later states unused), CTC to ft-1 (states frozen for t>=ft by
// the retained run-guard). 8-step register prefetch with sched_barriers.
// ---------------------------------------------------------------------------
__global__ __launch_bounds__(256) void k_dp(
    const float* __restrict__ lp_blank, const float* __restrict__ lp_label,
    const float* __restrict__ ctc_blank, const float* __restrict__ ctc_lse,
    const float* __restrict__ ctc_lab,
    const int* __restrict__ target,
    const int* __restrict__ flen, const int* __restrict__ tlen,
    float* __restrict__ out) {
  __shared__ float sA[256 * 66];             // RNNT lp_blank2[t][u], stride 66
  __shared__ __align__(16) float sB[16384];  // RNNT lp_label2 ; CTC raw2
  __shared__ float sC[256], sD[256];         // CTC blank2, lse2
  __shared__ float cT[129];
  const int tid = threadIdx.x;
  const int l = tid & 63;

  if (blockIdx.x < 4) {
    const int b = blockIdx.x;
    for (int i = tid; i < 16640; i += 256) {
      int r = i / 65, cidx = i - r * 65;
      sA[r * 66 + cidx] = lp_blank[b * 16640 + i];
    }
    {
      const f32x4* g2 = (const f32x4*)(lp_label + b * 16384);
      f32x4* s2 = (f32x4*)sB;
      for (int i = tid; i < 4096; i += 256) s2[i] = g2[i];
    }
    __syncthreads();
    if (tid < 64) {
      const int ft = flen[b], tl = tlen[b];
      const int dstar = ft - 1 + tl;
      const bool isown = (l == tl);
      const bool is64 = (tl == 64) && (l == 63);
      const int lc = (l >= 1) ? l - 1 : 0;

#define RLOAD(D0, VB, VL, VB64, VL64)                                          \
  _Pragma("unroll") for (int j = 0; j < 8; ++j) {                              \
    const int d_ = (D0) + j;                                                   \
    const int t_ = d_ - l;                                                     \
    const int tbc_ = (t_ < 1) ? 1 : (t_ > 255 ? 255 : t_);                     \
    const int tcc_ = (t_ < 0) ? 0 : (t_ > 255 ? 255 : t_);                     \
    VB[j] = sA[(tbc_ - 1) * 66 + l];                                           \
    VL[j] = (l == 0) ? NEGF : sB[tcc_ * 64 + lc];                              \
    const int t64_ = d_ - 64;                                                  \
    const int t64b_ = (t64_ < 1) ? 1 : (t64_ > 255 ? 255 : t64_);              \
    const int t64c_ = (t64_ < 0) ? 0 : (t64_ > 255 ? 255 : t64_);              \
    VB64[j] = sA[(t64b_ - 1) * 66 + 64];                                       \
    VL64[j] = sB[t64c_ * 64 + 63];                                             \
  }

      float cvb[8], cvl[8], cvb64[8], cvl64[8];
      RLOAD(1, cvb, cvl, cvb64, cvl64);
      float a = (l == 0) ? 0.0f : NEGF;
      float a64 = NEGF, cap = NEGF;
      for (int d0 = 1; d0 <= dstar; d0 += 8) {  // EARLY EXIT past dstar
        float nvb[8], nvl[8], nvb64[8], nvl64[8];
        RLOAD(d0 + 8, nvb, nvl, nvb64, nvl64);  // prefetch next block
        __builtin_amdgcn_sched_barrier(0);
#pragma unroll
        for (int j = 0; j < 8; ++j) {  // base-2 chain, no range predication
          const int d = d0 + j;
          float aleft = shfl_up1(a);
          float x = a + cvb[j];
          float y = aleft + cvl[j];            // lane 0: cvl = NEGF
          float nw = laddexp2_(x, y);
          float nw64 = laddexp2_(a64 + cvb64[j], a + cvl64[j]);  // old a
          a = nw;
          a64 = (l == 63) ? nw64 : a64;
          bool hit = (d == dstar);
          cap = (hit && isown) ? a : cap;
          cap = (hit && is64) ? a64 : cap;
        }
        __builtin_amdgcn_sched_barrier(0);
#pragma unroll
        for (int j = 0; j < 8; ++j) {
          cvb[j] = nvb[j];
          cvl[j] = nvl[j];
          cvb64[j] = nvb64[j];
          cvl64[j] = nvl64[j];
        }
      }
#undef RLOAD
      bool owner = (tl < 64) ? isown : (l == 63);
      if (owner)
        atomicAdd(out, -0.25f * LN2 * (cap + sA[(ft - 1) * 66 + tl]));
    }
  } else {
    const int b = blockIdx.x - 4;
    {
      const f32x4* g2 = (const f32x4*)(ctc_lab + b * 16384);
      f32x4* s2 = (f32x4*)sB;
      for (int i = tid; i < 4096; i += 256) s2[i] = g2[i];
      sC[tid] = ctc_blank[b * 256 + tid];
      sD[tid] = ctc_lse[b * 256 + tid];
    }
    __syncthreads();
    if (tid < 64) {
      const int ft = flen[b], tl = tlen[b];
      const int tg = target[b * Un + l];
      const int tgp = (l >= 1) ? target[b * Un + l - 1] : -1;
      const bool skip1 = (l >= 1) && (tg != tgp);

#define CLOAD(T0, EB, E1)                                                      \
  _Pragma("unroll") for (int j = 0; j < 8; ++j) {                              \
    const int tc_ = ((T0) + j > 255) ? 255 : (T0) + j;                         \
    EB[j] = sC[tc_];                                                           \
    E1[j] = sB[tc_ * 64 + l] - sD[tc_];                                        \
  }

      float ceb[8], ce1[8];
      CLOAD(1, ceb, ce1);
      float a0 = (l == 0) ? sC[0] : NEGF;
      float a1 = (l == 0) ? (sB[0] - sD[0]) : NEGF;
      float a2 = NEGF;
      for (int t0 = 1; t0 < ft; t0 += 8) {  // EARLY EXIT at ft (frozen past)
        float neb[8], ne1[8];
        CLOAD(t0 + 8, neb, ne1);
        __builtin_amdgcn_sched_barrier(0);
#pragma unroll
        for (int j = 0; j < 8; ++j) {
          const int t = t0 + j;
          float pm1 = shfl_up1(a1);
          pm1 = (l == 0) ? NEGF : pm1;
          float n0 = ceb[j] + laddexp2_(a0, pm1);
          float n1 = ce1[j] + laddexp3_2(a1, a0, skip1 ? pm1 : NEGF);
          float n2 = ceb[j] + laddexp2_(a2, a1);
          bool run = (t < ft);
          a0 = run ? n0 : a0;
          a1 = run ? n1 : a1;
          a2 = (run && (l == 63)) ? n2 : a2;
        }
        __builtin_amdgcn_sched_barrier(0);
#pragma unroll
        for (int j = 0; j < 8; ++j) {
          ceb[j] = neb[j];
          ce1[j] = ne1[j];
        }
      }
#undef CLOAD
      cT[2 * l] = a0;
      cT[2 * l + 1] = a1;
      if (l == 63) cT[128] = a2;
      __builtin_amdgcn_s_waitcnt(0);  // intra-wave lgkm drain before readback
      if (l == 0) {
        int sl = 2 * tl;
        float ll = laddexp2_(cT[sl], cT[sl - 1]);  // base-2 units
        float lb = (ll < NEGF * 0.7f) ? 0.0f : -ll;
        atomicAdd(out, CTCW * 0.25f * LN2 * lb);
      }
    }
  }
}

// ---------------------------------------------------------------------------
extern "C" void kernel_launch(void* const* d_in, const int* in_sizes, int n_in,
                              void* d_out, int out_size, void* d_ws, size_t ws_size,
                              hipStream_t stream) {
  (void)in_sizes; (void)n_in; (void)out_size; (void)ws_size;
  const float* x_enc = (const float*)d_in[0];
  const float* x_dec = (const float*)d_in[1];
  const float* W_enc = (const float*)d_in[2];
  const float* b_enc = (const float*)d_in[3];
  const float* W_dec = (const float*)d_in[4];
  const float* b_dec = (const float*)d_in[5];
  const float* W_out = (const float*)d_in[6];
  const float* b_out = (const float*)d_in[7];
  const float* W_ctc = (const float*)d_in[8];
  const float* b_ctc = (const float*)d_in[9];
  const int* target = (const int*)d_in[10];
  const int* flen = (const int*)d_in[11];
  const int* tlen = (const int*)d_in[12];

  float* ws = (float*)d_ws;
  float* enc_lin = ws;                    // 262144
  float* dec_lin = ws + 262144;           // 66560
  float* lp_blank = ws + 328704;          // 66560
  float* lp_label = ws + 395264;          // 65536
  float* ctc_blank = ws + 460800;         // 1024
  float* ctc_lse = ws + 461824;           // 1024
  float* ctc_lab = ws + 462848;           // 65536
  unsigned short* Wt_out = (unsigned short*)(ws + 528384);  // 262144 bf16 (tiled)
  unsigned short* Wt_ctc = Wt_out + 262144;                 // 262144 bf16 (tiled)
  unsigned short* Wt_enc = (unsigned short*)lp_blank;       // 65536 bf16
  unsigned short* Wt_dec = (unsigned short*)lp_label;       // 65536 bf16
  float* out = (float*)d_out;

  k_prep<<<dim3(160), dim3(256), 0, stream>>>(
      W_enc, W_dec, W_out, W_ctc, Wt_enc, Wt_dec, Wt_out, Wt_ctc, out);
  k_lin<<<dim3(21), dim3(256), 0, stream>>>(
      x_enc, x_dec, Wt_enc, b_enc, Wt_dec, b_dec, enc_lin, dec_lin);
  k_join2<<<dim3(1056), dim3(256), 0, stream>>>(
      enc_lin, dec_lin, Wt_out, b_out, x_enc, Wt_ctc, b_ctc, target,
      lp_blank, lp_label, ctc_blank, ctc_lse, ctc_lab);
  k_dp<<<dim3(8), dim3(64 * 4), 0, stream>>>(
      lp_blank, lp_label, ctc_blank, ctc_lse, ctc_lab, target, flen, tlen, out);
}

// Round 17
// 120.252 us; speedup vs baseline: 1.3144x; 1.0134x over previous
//
#include <hip/hip_runtime.h>
#include <hip/hip_bf16.h>

#define Bn 4
#define Tn 256
#define Un 64
#define UP1 65
#define Vn 1024
#define Dn 256
#define Hn 256
#define BLANKC 1023
#define NEGF (-1.0e30f)
#define CTCW 0.3f
#define R2E 1.4426950408889634f  // 1/ln2
#define LN2 0.6931471805599453f

typedef __attribute__((ext_vector_type(8))) short short8;
typedef __attribute__((ext_vector_type(4))) float f32x4;
typedef __attribute__((ext_vector_type(4))) unsigned int u32x4;

static __device__ __forceinline__ unsigned short f2bf(float f) {
  unsigned int u = __float_as_uint(f);
  u += 0x7FFFu + ((u >> 16) & 1u);
  return (unsigned short)(u >> 16);
}
static __device__ __forceinline__ unsigned int pack2bf(float a, float b) {
  return (unsigned int)f2bf(a) | ((unsigned int)f2bf(b) << 16);
}
static __device__ __forceinline__ float ftanh(float x) {
  float e = __expf(2.0f * x);
  return 1.0f - 2.0f / (e + 1.0f);
}
static __device__ __forceinline__ float ex2(float x) {
  return __builtin_amdgcn_exp2f(x);
}
static __device__ __forceinline__ float lg2(float x) {
  return __builtin_amdgcn_logf(x);
}
// base-2 logaddexp; safe for +-1e30 garbage magnitudes (max-form).
static __device__ __forceinline__ float laddexp2_(float x, float y) {
  float m = fmaxf(x, y);
  float d = y - x;
  return m + lg2(1.0f + ex2(-fabsf(d)));
}
static __device__ __forceinline__ float laddexp3_2(float a, float b, float c) {
  float m = fmaxf(fmaxf(a, b), c);
  return m + lg2(ex2(a - m) + ex2(b - m) + ex2(c - m));
}
// lane i <- lane i-1 (lane 0 gets 0; callers mask lane 0). DPP wave_shr:1.
static __device__ __forceinline__ float shfl_up1(float x) {
  int r = __builtin_amdgcn_update_dpp(0, __float_as_int(x), 0x138, 0xF, 0xF, false);
  return __int_as_float(r);
}

// ---------------------------------------------------------------------------
// K1 k_prep: W_out/W_ctc -> step-tiled bf16 layout Wt2[s=(c,ks)][sub][col][8k];
// W_enc/W_dec -> flat bf16 transpose. Zeroes d_out.
// ---------------------------------------------------------------------------
__global__ __launch_bounds__(256) void k_prep(
    const float* __restrict__ W_enc, const float* __restrict__ W_dec,
    const float* __restrict__ W_out, const float* __restrict__ W_ctc,
    unsigned short* __restrict__ Wt_enc, unsigned short* __restrict__ Wt_dec,
    unsigned short* __restrict__ Wt_out, unsigned short* __restrict__ Wt_ctc,
    float* __restrict__ out) {
  const int blk = blockIdx.x, tid = threadIdx.x;
  if (blk == 0 && tid == 0) out[0] = 0.0f;
  __shared__ float tilebuf[64][65];
  if (blk < 128) {
    const float* Wsrc = (blk < 64) ? W_out : W_ctc;
    unsigned short* Wd = (blk < 64) ? Wt_out : Wt_ctc;
    const int tt = blk & 63;
    const int k0 = (tt & 3) * 64, v0 = (tt >> 2) * 64;
#pragma unroll
    for (int rep = 0; rep < 16; ++rep) {
      int e = rep * 256 + tid;
      int rr = e >> 6, cc = e & 63;  // rr: k-off, cc: n-off
      tilebuf[rr][cc] = Wsrc[(k0 + rr) * 1024 + (v0 + cc)];
    }
    __syncthreads();
#pragma unroll
    for (int rep = 0; rep < 16; ++rep) {
      int e = rep * 256 + tid;
      int nn = e >> 6, kk = e & 63;
      int n = v0 + nn, k = k0 + kk;
      int c = n >> 8, col = n & 255;
      int ks = k >> 5, sub = (k >> 3) & 3, k7 = k & 7;
      Wd[(c * 8 + ks) * 8192 + sub * 2048 + col * 8 + k7] = f2bf(tilebuf[kk][nn]);
    }
  } else {
    const float* Wsrc = (blk < 144) ? W_enc : W_dec;
    unsigned short* Wd = (blk < 144) ? Wt_enc : Wt_dec;
    const int tt = (blk - 128) & 15;
    const int k0 = (tt & 3) * 64, v0 = (tt >> 2) * 64;
#pragma unroll
    for (int rep = 0; rep < 16; ++rep) {
      int e = rep * 256 + tid;
      int rr = e >> 6, cc = e & 63;
      tilebuf[rr][cc] = Wsrc[(k0 + rr) * 256 + (v0 + cc)];
    }
    __syncthreads();
#pragma unroll
    for (int rep = 0; rep < 16; ++rep) {
      int e = rep * 256 + tid;
      int rr = e >> 6, cc = e & 63;
      Wd[(v0 + rr) * 256 + (k0 + cc)] = f2bf(tilebuf[cc][rr]);
    }
  }
}

// ---------------------------------------------------------------------------
// K1b k_lin: enc_lin / dec_lin via MFMA. 32-ROW TILES (41 blocks, 2x the
// parallelism of the 64-row version; this kernel is latency-bound on a tiny
// grid). blocks 0-31: enc; 32-40: dec.
// ---------------------------------------------------------------------------
__global__ __launch_bounds__(256) void k_lin(
    const float* __restrict__ x_enc, const float* __restrict__ x_dec,
    const unsigned short* __restrict__ Wt_enc, const float* __restrict__ b_enc,
    const unsigned short* __restrict__ Wt_dec, const float* __restrict__ b_dec,
    float* __restrict__ enc_lin, float* __restrict__ dec_lin) {
  __shared__ __align__(16) char Asw[32 * 512];
  const int tid = threadIdx.x;
  const int w = tid >> 6, l = tid & 63;
  const int l15 = l & 15, l4 = l >> 4;
  const bool enc = blockIdx.x < 32;
  const int m0 = enc ? blockIdx.x * 32 : (blockIdx.x - 32) * 32;
  const int Mlim = enc ? 1024 : 260;
  const float* xp = enc ? x_enc : x_dec;
  const unsigned short* Wt = enc ? Wt_enc : Wt_dec;
  const float* bias = enc ? b_enc : b_dec;
  float* outp = enc ? enc_lin : dec_lin;

#pragma unroll
  for (int it = 0; it < 4; ++it) {
    int e = (it << 8) + tid;
    int i = e >> 5;                 // row 0..31
    int k0 = (e & 31) << 3;
    int r = m0 + i;
    if (r > Mlim - 1) r = Mlim - 1;
    const float* sp = xp + r * 256 + k0;
    f32x4 e0 = *(const f32x4*)sp;
    f32x4 e1 = *(const f32x4*)(sp + 4);
    u32x4 pv;
    pv[0] = pack2bf(e0[0], e0[1]);
    pv[1] = pack2bf(e0[2], e0[3]);
    pv[2] = pack2bf(e1[0], e1[1]);
    pv[3] = pack2bf(e1[2], e1[3]);
    int byt = (i << 9) + (k0 << 1);
    byt ^= (i & 7) << 4;
    *(u32x4*)(Asw + byt) = pv;
  }
  __syncthreads();

  const int nb = w * 64;
  f32x4 acc[2][4] = {};
#pragma unroll
  for (int ks = 0; ks < 8; ++ks) {
    int k = ks * 32 + l4 * 8;
    short8 af[2];
#pragma unroll
    for (int mt = 0; mt < 2; ++mt) {
      int i = mt * 16 + l15;
      int byt = (i << 9) + (k << 1);
      byt ^= (i & 7) << 4;
      af[mt] = *(const short8*)(Asw + byt);
    }
    short8 bfr[4];
#pragma unroll
    for (int nt = 0; nt < 4; ++nt) {
      int n = nb + nt * 16 + l15;
      bfr[nt] = *(const short8*)(Wt + n * 256 + k);
    }
#pragma unroll
    for (int mt = 0; mt < 2; ++mt)
#pragma unroll
      for (int nt = 0; nt < 4; ++nt)
        acc[mt][nt] = __builtin_amdgcn_mfma_f32_16x16x32_bf16(
            af[mt], bfr[nt], acc[mt][nt], 0, 0, 0);
  }
  float biasv[4];
#pragma unroll
  for (int nt = 0; nt < 4; ++nt) biasv[nt] = bias[nb + nt * 16 + l15];
#pragma unroll
  for (int mt = 0; mt < 2; ++mt)
#pragma unroll
    for (int rr = 0; rr < 4; ++rr) {
      int row = m0 + mt * 16 + l4 * 4 + rr;
      if (row < Mlim) {
#pragma unroll
        for (int nt = 0; nt < 4; ++nt)
          outp[row * 256 + nb + nt * 16 + l15] = acc[mt][nt][rr] + biasv[nt];
      }
    }
}

// ---------------------------------------------------------------------------
// K2 merged: blocks 0-15 = CTC head; blocks 16-1055 = joiner.
// Best-measured structure (join ~70.5us): 64-row blocks, DEPTH-2 even/odd
// register B pipeline (VGPR ~120, barrier-free K-loop) + chunk rotation +
// base-2 folding. NEW: s_setprio(1) around MFMA clusters (T5; waves here are
// independent, the regime where setprio measured +).
// ---------------------------------------------------------------------------
__global__ __launch_bounds__(256) void k_join2(
    const float* __restrict__ enc_lin, const float* __restrict__ dec_lin,
    const unsigned short* __restrict__ Wt_out, const float* __restrict__ b_out,
    const float* __restrict__ x_enc,
    const unsigned short* __restrict__ Wt_ctc, const float* __restrict__ b_ctc,
    const int* __restrict__ target,
    float* __restrict__ lp_blank, float* __restrict__ lp_label,
    float* __restrict__ ctc_blank, float* __restrict__ ctc_lse,
    float* __restrict__ ctc_lab) {
  __shared__ __align__(16) char Asw[64 * 512];    // 32KB A tile
  __shared__ float s_psum[4][64];
  __shared__ float s_blank[64], s_label[64];
  __shared__ int s_tgt[64];

  const int tid = threadIdx.x;
  const int w = tid >> 6, l = tid & 63;
  const int l15 = l & 15, l4 = l >> 4;
  const int bid = blockIdx.x;

  const bool joiner = bid >= 16;
  const unsigned short* Wt = joiner ? Wt_out : Wt_ctc;
  const float* bias = joiner ? b_out : b_ctc;

  // B base: step s, col = w*64 + nt*16 + l15, sub = l4.
  const unsigned short* tb = Wt + l4 * 2048 + (w * 64 + l15) * 8;

  short8 bE[4], bO[4];
#define LOADB(REG, S)                                                          \
  {                                                                            \
    const unsigned short* p_ = tb + (S)*8192;                                  \
    _Pragma("unroll") for (int nt = 0; nt < 4; ++nt)                           \
        REG[nt] = *(const short8*)(p_ + nt * 128);                             \
  }
  {
    const int sc0 = (bid & 3) * 8;
    LOADB(bE, sc0 + 0)
    LOADB(bO, sc0 + 1)
  }

  int b, r0 = 0, g0 = 0;
  if (joiner) {
    const int jbid = bid - 16;
    b = jbid / 260;
    r0 = (jbid % 260) * 64;
#pragma unroll
    for (int it = 0; it < 8; ++it) {
      int e = (it << 8) + tid;
      int i = e >> 5;
      int k0 = (e & 31) << 3;
      int r = r0 + i;
      int t = r / 65;
      int u = r - t * 65;
      const float* ep = enc_lin + ((b * Tn + t) * Hn + k0);
      const float* dp = dec_lin + ((b * UP1 + u) * Hn + k0);
      f32x4 e0 = *(const f32x4*)ep;
      f32x4 e1 = *(const f32x4*)(ep + 4);
      f32x4 d0 = *(const f32x4*)dp;
      f32x4 d1 = *(const f32x4*)(dp + 4);
      u32x4 pv;
      pv[0] = pack2bf(ftanh(e0[0] + d0[0]) * R2E, ftanh(e0[1] + d0[1]) * R2E);
      pv[1] = pack2bf(ftanh(e0[2] + d0[2]) * R2E, ftanh(e0[3] + d0[3]) * R2E);
      pv[2] = pack2bf(ftanh(e1[0] + d1[0]) * R2E, ftanh(e1[1] + d1[1]) * R2E);
      pv[3] = pack2bf(ftanh(e1[2] + d1[2]) * R2E, ftanh(e1[3] + d1[3]) * R2E);
      int byt = (i << 9) + (k0 << 1);
      byt ^= (i & 7) << 4;
      *(u32x4*)(Asw + byt) = pv;
    }
    if (tid < 64) {
      int u = (r0 + tid) % 65;
      s_tgt[tid] = (u < Un) ? target[b * Un + u] : -1;
    }
  } else {
    g0 = bid * 64;
    b = g0 >> 8;
#pragma unroll
    for (int it = 0; it < 8; ++it) {
      int e = (it << 8) + tid;
      int i = e >> 5;
      int k0 = (e & 31) << 3;
      const float* sp = x_enc + (g0 + i) * Dn + k0;
      f32x4 e0 = *(const f32x4*)sp;
      f32x4 e1 = *(const f32x4*)(sp + 4);
      u32x4 pv;
      pv[0] = pack2bf(e0[0] * R2E, e0[1] * R2E);
      pv[1] = pack2bf(e0[2] * R2E, e0[3] * R2E);
      pv[2] = pack2bf(e1[0] * R2E, e1[1] * R2E);
      pv[3] = pack2bf(e1[2] * R2E, e1[3] * R2E);
      int byt = (i << 9) + (k0 << 1);
      byt ^= (i & 7) << 4;
      *(u32x4*)(Asw + byt) = pv;
    }
    if (tid < 64) s_tgt[tid] = target[b * Un + tid];
  }
  __syncthreads();  // A tile + s_tgt ready; the ONLY pre-epilogue barrier

  float ssum[16];
#pragma unroll
  for (int j = 0; j < 16; ++j) ssum[j] = 0.0f;

#define MFMASTEP(REG, KS)                                                      \
  {                                                                            \
    __builtin_amdgcn_s_setprio(1);                                             \
    const int k_ = (KS)*32 + l4 * 8;                                           \
    _Pragma("unroll") for (int mt = 0; mt < 4; ++mt) {                         \
      int i_ = mt * 16 + l15;                                                  \
      int byt_ = ((i_ << 9) + (k_ << 1)) ^ ((i_ & 7) << 4);                    \
      short8 af_ = *(const short8*)(Asw + byt_);                               \
      _Pragma("unroll") for (int nt = 0; nt < 4; ++nt)                         \
          acc[mt][nt] = __builtin_amdgcn_mfma_f32_16x16x32_bf16(               \
              af_, REG[nt], acc[mt][nt], 0, 0, 0);                             \
    }                                                                          \
    __builtin_amdgcn_s_setprio(0);                                             \
  }
#define SB __builtin_amdgcn_sched_barrier(0)

#pragma unroll 1
  for (int cr = 0; cr < 4; ++cr) {
    const int cc = (cr + bid) & 3;             // rotated chunk id (uniform)
    const int sc = cc * 8;
    const int scn = ((cr + 1 + bid) & 3) * 8;  // next chunk's step base
    f32x4 acc[4][4] = {};
    MFMASTEP(bE, 0) LOADB(bE, sc + 2) SB;
    MFMASTEP(bO, 1) LOADB(bO, sc + 3) SB;
    MFMASTEP(bE, 2) LOADB(bE, sc + 4) SB;
    MFMASTEP(bO, 3) LOADB(bO, sc + 5) SB;
    MFMASTEP(bE, 4) LOADB(bE, sc + 6) SB;
    MFMASTEP(bO, 5) LOADB(bO, sc + 7) SB;
    MFMASTEP(bE, 6) LOADB(bE, (cr < 3) ? scn + 0 : sc + 6) SB;
    MFMASTEP(bO, 7) LOADB(bO, (cr < 3) ? scn + 1 : sc + 7) SB;

    const int nb = cc * 256 + w * 64;
    float biasv[4];
#pragma unroll
    for (int nt = 0; nt < 4; ++nt) biasv[nt] = bias[nb + nt * 16 + l15] * R2E;
#pragma unroll
    for (int mt = 0; mt < 4; ++mt)
#pragma unroll
      for (int nt = 0; nt < 4; ++nt)
#pragma unroll
        for (int rr = 0; rr < 4; ++rr) acc[mt][nt][rr] += biasv[nt];

    if (joiner) {
      if (cc == 3 && w == 3 && l15 == 15) {
#pragma unroll
        for (int mt = 0; mt < 4; ++mt)
#pragma unroll
          for (int rr = 0; rr < 4; ++rr)
            s_blank[mt * 16 + l4 * 4 + rr] = acc[mt][3][rr];
      }
#pragma unroll
      for (int mt = 0; mt < 4; ++mt)
#pragma unroll
        for (int rr = 0; rr < 4; ++rr) {
          int row = mt * 16 + l4 * 4 + rr;
          int tg = s_tgt[row];
          if ((tg >> 8) == cc && ((tg >> 6) & 3) == w && (tg & 15) == l15) {
            int ntv = (tg >> 4) & 3;
            float v01 = (ntv & 1) ? acc[mt][1][rr] : acc[mt][0][rr];
            float v23 = (ntv & 1) ? acc[mt][3][rr] : acc[mt][2][rr];
            s_label[row] = (ntv & 2) ? v23 : v01;
          }
        }
    } else {
      if (cc == 3 && w == 3 && l15 == 15) {
#pragma unroll
        for (int mt = 0; mt < 4; ++mt)
#pragma unroll
          for (int rr = 0; rr < 4; ++rr)
            s_blank[mt * 16 + l4 * 4 + rr] = acc[mt][3][rr];
      }
#pragma unroll 1
      for (int u = 0; u < 64; ++u) {
        int tgu = s_tgt[u];
        if ((tgu >> 8) == cc && ((tgu >> 6) & 3) == w) {
          int ntv = (tgu >> 4) & 3;
          if ((tgu & 15) == l15) {
#pragma unroll
            for (int mt = 0; mt < 4; ++mt)
#pragma unroll
              for (int rr = 0; rr < 4; ++rr) {
                float v01 = (ntv & 1) ? acc[mt][1][rr] : acc[mt][0][rr];
                float v23 = (ntv & 1) ? acc[mt][3][rr] : acc[mt][2][rr];
                float v = (ntv & 2) ? v23 : v01;
                ctc_lab[(g0 + mt * 16 + l4 * 4 + rr) * 64 + u] = v;
              }
          }
        }
      }
    }
    // base-2 exp-sum: acc already in log2 units, raw v_exp (no mul)
#pragma unroll
    for (int mt = 0; mt < 4; ++mt)
#pragma unroll
      for (int rr = 0; rr < 4; ++rr)
        ssum[mt * 4 + rr] += ex2(acc[mt][0][rr]) + ex2(acc[mt][1][rr]) +
                             ex2(acc[mt][2][rr]) + ex2(acc[mt][3][rr]);
  }
#undef MFMASTEP
#undef LOADB
#undef SB

#pragma unroll
  for (int ms = 1; ms < 16; ms <<= 1)
#pragma unroll
    for (int j = 0; j < 16; ++j) ssum[j] += __shfl_xor(ssum[j], ms, 64);
  if (l15 == 0) {
#pragma unroll
    for (int j = 0; j < 16; ++j)
      s_psum[w][(j >> 2) * 16 + l4 * 4 + (j & 3)] = ssum[j];
  }
  __syncthreads();

  if (tid < 64) {
    float tot = s_psum[0][tid] + s_psum[1][tid] + s_psum[2][tid] + s_psum[3][tid];
    float lse = lg2(tot);  // base-2 LSE
    if (joiner) {
      int r = r0 + tid;
      int t = r / 65;
      int u = r - t * 65;
      lp_blank[(b * Tn + t) * UP1 + u] = s_blank[tid] - lse;   // base-2 units
      if (u < Un) lp_label[(b * Tn + t) * Un + u] = s_label[tid] - lse;
    } else {
      ctc_blank[g0 + tid] = s_blank[tid] - lse;                // base-2 units
      ctc_lse[g0 + tid] = lse;
    }
  }
}

// ---------------------------------------------------------------------------
// K3 k_dp: blocks 0-3 RNNT anti-diagonal DP; blocks 4-7 CTC DP.
// Base-2 inputs; native v_exp/v_log chain; *LN2 once at the atomicAdd.
// Early-exit bounds + UNIFORM-BRANCH LEAN BODIES (new): the cap-capture
// cndmasks (RNNT) and run-guard cndmasks (CTC) only execute in the single
// 8-step block containing dstar / crossing ft; all other blocks run a lean
// body where those predicates are provably constant. Identical math.
// ---------------------------------------------------------------------------
__global__ __launch_bounds__(256) void k_dp(
    const float* __restrict__ lp_blank, const float* __restrict__ lp_label,
    const float* __restrict__ ctc_blank, const float* __restrict__ ctc_lse,
    const float* __restrict__ ctc_lab,
    const int* __restrict__ target,
    const int* __restrict__ flen, const int* __restrict__ tlen,
    float* __restrict__ out) {
  __shared__ float sA[256 * 66];             // RNNT lp_blank2[t][u], stride 66
  __shared__ __align__(16) float sB[16384];  // RNNT lp_label2 ; CTC raw2
  __shared__ float sC[256], sD[256];         // CTC blank2, lse2
  __shared__ float cT[129];
  const int tid = threadIdx.x;
  const int l = tid & 63;

  if (blockIdx.x < 4) {
    const int b = blockIdx.x;
    for (int i = tid; i < 16640; i += 256) {
      int r = i / 65, cidx = i - r * 65;
      sA[r * 66 + cidx] = lp_blank[b * 16640 + i];
    }
    {
      const f32x4* g2 = (const f32x4*)(lp_label + b * 16384);
      f32x4* s2 = (f32x4*)sB;
      for (int i = tid; i < 4096; i += 256) s2[i] = g2[i];
    }
    __syncthreads();
    if (tid < 64) {
      const int ft = flen[b], tl = tlen[b];
      const int dstar = ft - 1 + tl;
      const bool isown = (l == tl);
      const bool is64 = (tl == 64) && (l == 63);
      const int lc = (l >= 1) ? l - 1 : 0;

#define RLOAD(D0, VB, VL, VB64, VL64)                                          \
  _Pragma("unroll") for (int j = 0; j < 8; ++j) {                              \
    const int d_ = (D0) + j;                                                   \
    const int t_ = d_ - l;                                                     \
    const int tbc_ = (t_ < 1) ? 1 : (t_ > 255 ? 255 : t_);                     \
    const int tcc_ = (t_ < 0) ? 0 : (t_ > 255 ? 255 : t_);                     \
    VB[j] = sA[(tbc_ - 1) * 66 + l];                                           \
    VL[j] = (l == 0) ? NEGF : sB[tcc_ * 64 + lc];                              \
    const int t64_ = d_ - 64;                                                  \
    const int t64b_ = (t64_ < 1) ? 1 : (t64_ > 255 ? 255 : t64_);              \
    const int t64c_ = (t64_ < 0) ? 0 : (t64_ > 255 ? 255 : t64_);              \
    VB64[j] = sA[(t64b_ - 1) * 66 + 64];                                       \
    VL64[j] = sB[t64c_ * 64 + 63];                                             \
  }

      float cvb[8], cvl[8], cvb64[8], cvl64[8];
      RLOAD(1, cvb, cvl, cvb64, cvl64);
      float a = (l == 0) ? 0.0f : NEGF;
      float a64 = NEGF, cap = NEGF;
      for (int d0 = 1; d0 <= dstar; d0 += 8) {  // early exit past dstar
        float nvb[8], nvl[8], nvb64[8], nvl64[8];
        RLOAD(d0 + 8, nvb, nvl, nvb64, nvl64);  // prefetch next block
        __builtin_amdgcn_sched_barrier(0);
        const bool hashit = ((unsigned)(dstar - d0)) < 8u;  // uniform
        if (hashit) {
#pragma unroll
          for (int j = 0; j < 8; ++j) {  // full body (cap capture)
            const int d = d0 + j;
            float aleft = shfl_up1(a);
            float x = a + cvb[j];
            float y = aleft + cvl[j];
            float nw = laddexp2_(x, y);
            float nw64 = laddexp2_(a64 + cvb64[j], a + cvl64[j]);
            a = nw;
            a64 = (l == 63) ? nw64 : a64;
            bool hit = (d == dstar);
            cap = (hit && isown) ? a : cap;
            cap = (hit && is64) ? a64 : cap;
          }
        } else {
#pragma unroll
          for (int j = 0; j < 8; ++j) {  // lean body (no cap checks)
            float aleft = shfl_up1(a);
            float x = a + cvb[j];
            float y = aleft + cvl[j];
            float nw = laddexp2_(x, y);
            float nw64 = laddexp2_(a64 + cvb64[j], a + cvl64[j]);
            a = nw;
            a64 = (l == 63) ? nw64 : a64;
          }
        }
        __builtin_amdgcn_sched_barrier(0);
#pragma unroll
        for (int j = 0; j < 8; ++j) {
          cvb[j] = nvb[j];
          cvl[j] = nvl[j];
          cvb64[j] = nvb64[j];
          cvl64[j] = nvl64[j];
        }
      }
#undef RLOAD
      bool owner = (tl < 64) ? isown : (l == 63);
      if (owner)
        atomicAdd(out, -0.25f * LN2 * (cap + sA[(ft - 1) * 66 + tl]));
    }
  } else {
    const int b = blockIdx.x - 4;
    {
      const f32x4* g2 = (const f32x4*)(ctc_lab + b * 16384);
      f32x4* s2 = (f32x4*)sB;
      for (int i = tid; i < 4096; i += 256) s2[i] = g2[i];
      sC[tid] = ctc_blank[b * 256 + tid];
      sD[tid] = ctc_lse[b * 256 + tid];
    }
    __syncthreads();
    if (tid < 64) {
      const int ft = flen[b], tl = tlen[b];
      const int tg = target[b * Un + l];
      const int tgp = (l >= 1) ? target[b * Un + l - 1] : -1;
      const bool skip1 = (l >= 1) && (tg != tgp);

#define CLOAD(T0, EB, E1)                                                      \
  _Pragma("unroll") for (int j = 0; j < 8; ++j) {                              \
    const int tc_ = ((T0) + j > 255) ? 255 : (T0) + j;                         \
    EB[j] = sC[tc_];                                                           \
    E1[j] = sB[tc_ * 64 + l] - sD[tc_];                                        \
  }

      float ceb[8], ce1[8];
      CLOAD(1, ceb, ce1);
      float a0 = (l == 0) ? sC[0] : NEGF;
      float a1 = (l == 0) ? (sB[0] - sD[0]) : NEGF;
      float a2 = NEGF;
      for (int t0 = 1; t0 < ft; t0 += 8) {  // early exit at ft (frozen past)
        float neb[8], ne1[8];
        CLOAD(t0 + 8, neb, ne1);
        __builtin_amdgcn_sched_barrier(0);
        const bool alive = (t0 + 8 <= ft);  // uniform: all 8 steps run
        if (alive) {
#pragma unroll
          for (int j = 0; j < 8; ++j) {  // lean body (no run guards)
            float pm1 = shfl_up1(a1);
            pm1 = (l == 0) ? NEGF : pm1;
            float n0 = ceb[j] + laddexp2_(a0, pm1);
            float n1 = ce1[j] + laddexp3_2(a1, a0, skip1 ? pm1 : NEGF);
            float n2 = ceb[j] + laddexp2_(a2, a1);
            a0 = n0;
            a1 = n1;
            a2 = (l == 63) ? n2 : a2;
          }
        } else {
#pragma unroll
          for (int j = 0; j < 8; ++j) {  // tail body (run guards)
            const int t = t0 + j;
            float pm1 = shfl_up1(a1);
            pm1 = (l == 0) ? NEGF : pm1;
            float n0 = ceb[j] + laddexp2_(a0, pm1);
            float n1 = ce1[j] + laddexp3_2(a1, a0, skip1 ? pm1 : NEGF);
            float n2 = ceb[j] + laddexp2_(a2, a1);
            bool run = (t < ft);
            a0 = run ? n0 : a0;
            a1 = run ? n1 : a1;
            a2 = (run && (l == 63)) ? n2 : a2;
          }
        }
        __builtin_amdgcn_sched_barrier(0);
#pragma unroll
        for (int j = 0; j < 8; ++j) {
          ceb[j] = neb[j];
          ce1[j] = ne1[j];
        }
      }
#undef CLOAD
      cT[2 * l] = a0;
      cT[2 * l + 1] = a1;
      if (l == 63) cT[128] = a2;
      __builtin_amdgcn_s_waitcnt(0);  // intra-wave lgkm drain before readback
      if (l == 0) {
        int sl = 2 * tl;
        float ll = laddexp2_(cT[sl], cT[sl - 1]);  // base-2 units
        float lb = (ll < NEGF * 0.7f) ? 0.0f : -ll;
        atomicAdd(out, CTCW * 0.25f * LN2 * lb);
      }
    }
  }
}

// ---------------------------------------------------------------------------
extern "C" void kernel_launch(void* const* d_in, const int* in_sizes, int n_in,
                              void* d_out, int out_size, void* d_ws, size_t ws_size,
                              hipStream_t stream) {
  (void)in_sizes; (void)n_in; (void)out_size; (void)ws_size;
  const float* x_enc = (const float*)d_in[0];
  const float* x_dec = (const float*)d_in[1];
  const float* W_enc = (const float*)d_in[2];
  const float* b_enc = (const float*)d_in[3];
  const float* W_dec = (const float*)d_in[4];
  const float* b_dec = (const float*)d_in[5];
  const float* W_out = (const float*)d_in[6];
  const float* b_out = (const float*)d_in[7];
  const float* W_ctc = (const float*)d_in[8];
  const float* b_ctc = (const float*)d_in[9];
  const int* target = (const int*)d_in[10];
  const int* flen = (const int*)d_in[11];
  const int* tlen = (const int*)d_in[12];

  float* ws = (float*)d_ws;
  float* enc_lin = ws;                    // 262144
  float* dec_lin = ws + 262144;           // 66560
  float* lp_blank = ws + 328704;          // 66560
  float* lp_label = ws + 395264;          // 65536
  float* ctc_blank = ws + 460800;         // 1024
  float* ctc_lse = ws + 461824;           // 1024
  float* ctc_lab = ws + 462848;           // 65536
  unsigned short* Wt_out = (unsigned short*)(ws + 528384);  // 262144 bf16 (tiled)
  unsigned short* Wt_ctc = Wt_out + 262144;                 // 262144 bf16 (tiled)
  unsigned short* Wt_enc = (unsigned short*)lp_blank;       // 65536 bf16
  unsigned short* Wt_dec = (unsigned short*)lp_label;       // 65536 bf16
  float* out = (float*)d_out;

  k_prep<<<dim3(160), dim3(256), 0, stream>>>(
      W_enc, W_dec, W_out, W_ctc, Wt_enc, Wt_dec, Wt_out, Wt_ctc, out);
  k_lin<<<dim3(41), dim3(256), 0, stream>>>(
      x_enc, x_dec, Wt_enc, b_enc, Wt_dec, b_dec, enc_lin, dec_lin);
  k_join2<<<dim3(1056), dim3(256), 0, stream>>>(
      enc_lin, dec_lin, Wt_out, b_out, x_enc, Wt_ctc, b_ctc, target,
      lp_blank, lp_label, ctc_blank, ctc_lse, ctc_lab);
  k_dp<<<dim3(8), dim3(64 * 4), 0, stream>>>(
      lp_blank, lp_label, ctc_blank, ctc_lse, ctc_lab, target, flen, tlen, out);
}

// Round 18
// 113.687 us; speedup vs baseline: 1.3903x; 1.0577x over previous
//
#include <hip/hip_runtime.h>
#include <hip/hip_bf16.h>

#define Bn 4
#define Tn 256
#define Un 64
#define UP1 65
#define Vn 1024
#define Dn 256
#define Hn 256
#define BLANKC 1023
#define NEGF (-1.0e30f)
#define CTCW 0.3f
#define R2E 1.4426950408889634f  // 1/ln2
#define LN2 0.6931471805599453f

typedef __attribute__((ext_vector_type(8))) short short8;
typedef __attribute__((ext_vector_type(4))) float f32x4;
typedef __attribute__((ext_vector_type(4))) unsigned int u32x4;

static __device__ __forceinline__ unsigned short f2bf(float f) {
  unsigned int u = __float_as_uint(f);
  u += 0x7FFFu + ((u >> 16) & 1u);
  return (unsigned short)(u >> 16);
}
static __device__ __forceinline__ unsigned int pack2bf(float a, float b) {
  return (unsigned int)f2bf(a) | ((unsigned int)f2bf(b) << 16);
}
static __device__ __forceinline__ float ftanh(float x) {
  float e = __expf(2.0f * x);
  return 1.0f - 2.0f / (e + 1.0f);
}
static __device__ __forceinline__ float ex2(float x) {
  return __builtin_amdgcn_exp2f(x);
}
static __device__ __forceinline__ float lg2(float x) {
  return __builtin_amdgcn_logf(x);
}
// base-2 logaddexp; safe for +-1e30 garbage magnitudes (max-form).
static __device__ __forceinline__ float laddexp2_(float x, float y) {
  float m = fmaxf(x, y);
  float d = y - x;
  return m + lg2(1.0f + ex2(-fabsf(d)));
}
static __device__ __forceinline__ float laddexp3_2(float a, float b, float c) {
  float m = fmaxf(fmaxf(a, b), c);
  return m + lg2(ex2(a - m) + ex2(b - m) + ex2(c - m));
}
// lane i <- lane i-1 (lane 0 gets 0; callers mask lane 0). DPP wave_shr:1.
static __device__ __forceinline__ float shfl_up1(float x) {
  int r = __builtin_amdgcn_update_dpp(0, __float_as_int(x), 0x138, 0xF, 0xF, false);
  return __int_as_float(r);
}

// ---------------------------------------------------------------------------
// K1 k_pre (fused): blocks 0-127 = W_out/W_ctc step-tiled bf16 transpose
// (Wt2[s][sub][col][8k]); blocks 128-168 = enc_lin/dec_lin MFMA linears with
// B-fragments built DIRECTLY from W_enc/W_dec (f32 stride-256 reads, 64B-
// coalesced per 16 lanes, L2-resident) -> no transpose dependency, one launch.
// ---------------------------------------------------------------------------
__global__ __launch_bounds__(256) void k_pre(
    const float* __restrict__ x_enc, const float* __restrict__ x_dec,
    const float* __restrict__ W_enc, const float* __restrict__ b_enc,
    const float* __restrict__ W_dec, const float* __restrict__ b_dec,
    const float* __restrict__ W_out, const float* __restrict__ W_ctc,
    unsigned short* __restrict__ Wt_out, unsigned short* __restrict__ Wt_ctc,
    float* __restrict__ enc_lin, float* __restrict__ dec_lin,
    float* __restrict__ out) {
  const int blk = blockIdx.x, tid = threadIdx.x;
  if (blk == 0 && tid == 0) out[0] = 0.0f;
  const int w = tid >> 6, l = tid & 63;
  const int l15 = l & 15, l4 = l >> 4;

  if (blk < 128) {
    __shared__ float tilebuf[64][65];
    const float* Wsrc = (blk < 64) ? W_out : W_ctc;
    unsigned short* Wd = (blk < 64) ? Wt_out : Wt_ctc;
    const int tt = blk & 63;
    const int k0 = (tt & 3) * 64, v0 = (tt >> 2) * 64;
#pragma unroll
    for (int rep = 0; rep < 16; ++rep) {
      int e = rep * 256 + tid;
      int rr = e >> 6, cc = e & 63;  // rr: k-off, cc: n-off
      tilebuf[rr][cc] = Wsrc[(k0 + rr) * 1024 + (v0 + cc)];
    }
    __syncthreads();
#pragma unroll
    for (int rep = 0; rep < 16; ++rep) {
      int e = rep * 256 + tid;
      int nn = e >> 6, kk = e & 63;
      int n = v0 + nn, k = k0 + kk;
      int c = n >> 8, col = n & 255;
      int ks = k >> 5, sub = (k >> 3) & 3, k7 = k & 7;
      Wd[(c * 8 + ks) * 8192 + sub * 2048 + col * 8 + k7] = f2bf(tilebuf[kk][nn]);
    }
  } else {
    // ---- linear part (32-row tiles): blocks 128-159 enc, 160-168 dec ----
    __shared__ __align__(16) char Asw[32 * 512];
    const int lb = blk - 128;
    const bool enc = lb < 32;
    const int m0 = enc ? lb * 32 : (lb - 32) * 32;
    const int Mlim = enc ? 1024 : 260;
    const float* xp = enc ? x_enc : x_dec;
    const float* Wsrc = enc ? W_enc : W_dec;
    const float* bias = enc ? b_enc : b_dec;
    float* outp = enc ? enc_lin : dec_lin;

#pragma unroll
    for (int it = 0; it < 4; ++it) {
      int e = (it << 8) + tid;
      int i = e >> 5;                 // row 0..31
      int k0 = (e & 31) << 3;
      int r = m0 + i;
      if (r > Mlim - 1) r = Mlim - 1;
      const float* sp = xp + r * 256 + k0;
      f32x4 e0 = *(const f32x4*)sp;
      f32x4 e1 = *(const f32x4*)(sp + 4);
      u32x4 pv;
      pv[0] = pack2bf(e0[0], e0[1]);
      pv[1] = pack2bf(e0[2], e0[3]);
      pv[2] = pack2bf(e1[0], e1[1]);
      pv[3] = pack2bf(e1[2], e1[3]);
      int byt = (i << 9) + (k0 << 1);
      byt ^= (i & 7) << 4;
      *(u32x4*)(Asw + byt) = pv;
    }
    __syncthreads();

    const int nb = w * 64;
    f32x4 acc[2][4] = {};
#pragma unroll
    for (int ks = 0; ks < 8; ++ks) {
      int k = ks * 32 + l4 * 8;
      short8 af[2];
#pragma unroll
      for (int mt = 0; mt < 2; ++mt) {
        int i = mt * 16 + l15;
        int byt = (i << 9) + (k << 1);
        byt ^= (i & 7) << 4;
        af[mt] = *(const short8*)(Asw + byt);
      }
      short8 bfr[4];
#pragma unroll
      for (int nt = 0; nt < 4; ++nt) {
        int n = nb + nt * 16 + l15;
        const float* wp = Wsrc + k * 256 + n;
        short8 v;
#pragma unroll
        for (int j = 0; j < 8; ++j) v[j] = (short)f2bf(wp[j * 256]);
        bfr[nt] = v;
      }
#pragma unroll
      for (int mt = 0; mt < 2; ++mt)
#pragma unroll
        for (int nt = 0; nt < 4; ++nt)
          acc[mt][nt] = __builtin_amdgcn_mfma_f32_16x16x32_bf16(
              af[mt], bfr[nt], acc[mt][nt], 0, 0, 0);
    }
    float biasv[4];
#pragma unroll
    for (int nt = 0; nt < 4; ++nt) biasv[nt] = bias[nb + nt * 16 + l15];
#pragma unroll
    for (int mt = 0; mt < 2; ++mt)
#pragma unroll
      for (int rr = 0; rr < 4; ++rr) {
        int row = m0 + mt * 16 + l4 * 4 + rr;
        if (row < Mlim) {
#pragma unroll
          for (int nt = 0; nt < 4; ++nt)
            outp[row * 256 + nb + nt * 16 + l15] = acc[mt][nt][rr] + biasv[nt];
        }
      }
  }
}

// ---------------------------------------------------------------------------
// K2 merged: blocks 0-15 = CTC head; blocks 16-1055 = joiner.
// Measured-best structure (join ~70.5us): 64-row blocks, DEPTH-2 even/odd
// register B pipeline (VGPR ~120, barrier-free K-loop) + chunk rotation +
// base-2 folding. setprio REMOVED (R17 A/B: -1.8us with it).
// ---------------------------------------------------------------------------
__global__ __launch_bounds__(256) void k_join2(
    const float* __restrict__ enc_lin, const float* __restrict__ dec_lin,
    const unsigned short* __restrict__ Wt_out, const float* __restrict__ b_out,
    const float* __restrict__ x_enc,
    const unsigned short* __restrict__ Wt_ctc, const float* __restrict__ b_ctc,
    const int* __restrict__ target,
    float* __restrict__ lp_blank, float* __restrict__ lp_label,
    float* __restrict__ ctc_blank, float* __restrict__ ctc_lse,
    float* __restrict__ ctc_lab) {
  __shared__ __align__(16) char Asw[64 * 512];    // 32KB A tile
  __shared__ float s_psum[4][64];
  __shared__ float s_blank[64], s_label[64];
  __shared__ int s_tgt[64];

  const int tid = threadIdx.x;
  const int w = tid >> 6, l = tid & 63;
  const int l15 = l & 15, l4 = l >> 4;
  const int bid = blockIdx.x;

  const bool joiner = bid >= 16;
  const unsigned short* Wt = joiner ? Wt_out : Wt_ctc;
  const float* bias = joiner ? b_out : b_ctc;

  // B base: step s, col = w*64 + nt*16 + l15, sub = l4.
  const unsigned short* tb = Wt + l4 * 2048 + (w * 64 + l15) * 8;

  short8 bE[4], bO[4];
#define LOADB(REG, S)                                                          \
  {                                                                            \
    const unsigned short* p_ = tb + (S)*8192;                                  \
    _Pragma("unroll") for (int nt = 0; nt < 4; ++nt)                           \
        REG[nt] = *(const short8*)(p_ + nt * 128);                             \
  }
  {
    const int sc0 = (bid & 3) * 8;
    LOADB(bE, sc0 + 0)
    LOADB(bO, sc0 + 1)
  }

  int b, r0 = 0, g0 = 0;
  if (joiner) {
    const int jbid = bid - 16;
    b = jbid / 260;
    r0 = (jbid % 260) * 64;
#pragma unroll
    for (int it = 0; it < 8; ++it) {
      int e = (it << 8) + tid;
      int i = e >> 5;
      int k0 = (e & 31) << 3;
      int r = r0 + i;
      int t = r / 65;
      int u = r - t * 65;
      const float* ep = enc_lin + ((b * Tn + t) * Hn + k0);
      const float* dp = dec_lin + ((b * UP1 + u) * Hn + k0);
      f32x4 e0 = *(const f32x4*)ep;
      f32x4 e1 = *(const f32x4*)(ep + 4);
      f32x4 d0 = *(const f32x4*)dp;
      f32x4 d1 = *(const f32x4*)(dp + 4);
      u32x4 pv;
      pv[0] = pack2bf(ftanh(e0[0] + d0[0]) * R2E, ftanh(e0[1] + d0[1]) * R2E);
      pv[1] = pack2bf(ftanh(e0[2] + d0[2]) * R2E, ftanh(e0[3] + d0[3]) * R2E);
      pv[2] = pack2bf(ftanh(e1[0] + d1[0]) * R2E, ftanh(e1[1] + d1[1]) * R2E);
      pv[3] = pack2bf(ftanh(e1[2] + d1[2]) * R2E, ftanh(e1[3] + d1[3]) * R2E);
      int byt = (i << 9) + (k0 << 1);
      byt ^= (i & 7) << 4;
      *(u32x4*)(Asw + byt) = pv;
    }
    if (tid < 64) {
      int u = (r0 + tid) % 65;
      s_tgt[tid] = (u < Un) ? target[b * Un + u] : -1;
    }
  } else {
    g0 = bid * 64;
    b = g0 >> 8;
#pragma unroll
    for (int it = 0; it < 8; ++it) {
      int e = (it << 8) + tid;
      int i = e >> 5;
      int k0 = (e & 31) << 3;
      const float* sp = x_enc + (g0 + i) * Dn + k0;
      f32x4 e0 = *(const f32x4*)sp;
      f32x4 e1 = *(const f32x4*)(sp + 4);
      u32x4 pv;
      pv[0] = pack2bf(e0[0] * R2E, e0[1] * R2E);
      pv[1] = pack2bf(e0[2] * R2E, e0[3] * R2E);
      pv[2] = pack2bf(e1[0] * R2E, e1[1] * R2E);
      pv[3] = pack2bf(e1[2] * R2E, e1[3] * R2E);
      int byt = (i << 9) + (k0 << 1);
      byt ^= (i & 7) << 4;
      *(u32x4*)(Asw + byt) = pv;
    }
    if (tid < 64) s_tgt[tid] = target[b * Un + tid];
  }
  __syncthreads();  // A tile + s_tgt ready; the ONLY pre-epilogue barrier

  float ssum[16];
#pragma unroll
  for (int j = 0; j < 16; ++j) ssum[j] = 0.0f;

#define MFMASTEP(REG, KS)                                                      \
  {                                                                            \
    const int k_ = (KS)*32 + l4 * 8;                                           \
    _Pragma("unroll") for (int mt = 0; mt < 4; ++mt) {                         \
      int i_ = mt * 16 + l15;                                                  \
      int byt_ = ((i_ << 9) + (k_ << 1)) ^ ((i_ & 7) << 4);                    \
      short8 af_ = *(const short8*)(Asw + byt_);                               \
      _Pragma("unroll") for (int nt = 0; nt < 4; ++nt)                         \
          acc[mt][nt] = __builtin_amdgcn_mfma_f32_16x16x32_bf16(               \
              af_, REG[nt], acc[mt][nt], 0, 0, 0);                             \
    }                                                                          \
  }
#define SB __builtin_amdgcn_sched_barrier(0)

#pragma unroll 1
  for (int cr = 0; cr < 4; ++cr) {
    const int cc = (cr + bid) & 3;             // rotated chunk id (uniform)
    const int sc = cc * 8;
    const int scn = ((cr + 1 + bid) & 3) * 8;  // next chunk's step base
    f32x4 acc[4][4] = {};
    MFMASTEP(bE, 0) LOADB(bE, sc + 2) SB;
    MFMASTEP(bO, 1) LOADB(bO, sc + 3) SB;
    MFMASTEP(bE, 2) LOADB(bE, sc + 4) SB;
    MFMASTEP(bO, 3) LOADB(bO, sc + 5) SB;
    MFMASTEP(bE, 4) LOADB(bE, sc + 6) SB;
    MFMASTEP(bO, 5) LOADB(bO, sc + 7) SB;
    MFMASTEP(bE, 6) LOADB(bE, (cr < 3) ? scn + 0 : sc + 6) SB;
    MFMASTEP(bO, 7) LOADB(bO, (cr < 3) ? scn + 1 : sc + 7) SB;

    const int nb = cc * 256 + w * 64;
    float biasv[4];
#pragma unroll
    for (int nt = 0; nt < 4; ++nt) biasv[nt] = bias[nb + nt * 16 + l15] * R2E;
#pragma unroll
    for (int mt = 0; mt < 4; ++mt)
#pragma unroll
      for (int nt = 0; nt < 4; ++nt)
#pragma unroll
        for (int rr = 0; rr < 4; ++rr) acc[mt][nt][rr] += biasv[nt];

    if (joiner) {
      if (cc == 3 && w == 3 && l15 == 15) {
#pragma unroll
        for (int mt = 0; mt < 4; ++mt)
#pragma unroll
          for (int rr = 0; rr < 4; ++rr)
            s_blank[mt * 16 + l4 * 4 + rr] = acc[mt][3][rr];
      }
#pragma unroll
      for (int mt = 0; mt < 4; ++mt)
#pragma unroll
        for (int rr = 0; rr < 4; ++rr) {
          int row = mt * 16 + l4 * 4 + rr;
          int tg = s_tgt[row];
          if ((tg >> 8) == cc && ((tg >> 6) & 3) == w && (tg & 15) == l15) {
            int ntv = (tg >> 4) & 3;
            float v01 = (ntv & 1) ? acc[mt][1][rr] : acc[mt][0][rr];
            float v23 = (ntv & 1) ? acc[mt][3][rr] : acc[mt][2][rr];
            s_label[row] = (ntv & 2) ? v23 : v01;
          }
        }
    } else {
      if (cc == 3 && w == 3 && l15 == 15) {
#pragma unroll
        for (int mt = 0; mt < 4; ++mt)
#pragma unroll
          for (int rr = 0; rr < 4; ++rr)
            s_blank[mt * 16 + l4 * 4 + rr] = acc[mt][3][rr];
      }
#pragma unroll 1
      for (int u = 0; u < 64; ++u) {
        int tgu = s_tgt[u];
        if ((tgu >> 8) == cc && ((tgu >> 6) & 3) == w) {
          int ntv = (tgu >> 4) & 3;
          if ((tgu & 15) == l15) {
#pragma unroll
            for (int mt = 0; mt < 4; ++mt)
#pragma unroll
              for (int rr = 0; rr < 4; ++rr) {
                float v01 = (ntv & 1) ? acc[mt][1][rr] : acc[mt][0][rr];
                float v23 = (ntv & 1) ? acc[mt][3][rr] : acc[mt][2][rr];
                float v = (ntv & 2) ? v23 : v01;
                ctc_lab[(g0 + mt * 16 + l4 * 4 + rr) * 64 + u] = v;
              }
          }
        }
      }
    }
    // base-2 exp-sum: acc already in log2 units, raw v_exp (no mul)
#pragma unroll
    for (int mt = 0; mt < 4; ++mt)
#pragma unroll
      for (int rr = 0; rr < 4; ++rr)
        ssum[mt * 4 + rr] += ex2(acc[mt][0][rr]) + ex2(acc[mt][1][rr]) +
                             ex2(acc[mt][2][rr]) + ex2(acc[mt][3][rr]);
  }
#undef MFMASTEP
#undef LOADB
#undef SB

#pragma unroll
  for (int ms = 1; ms < 16; ms <<= 1)
#pragma unroll
    for (int j = 0; j < 16; ++j) ssum[j] += __shfl_xor(ssum[j], ms, 64);
  if (l15 == 0) {
#pragma unroll
    for (int j = 0; j < 16; ++j)
      s_psum[w][(j >> 2) * 16 + l4 * 4 + (j & 3)] = ssum[j];
  }
  __syncthreads();

  if (tid < 64) {
    float tot = s_psum[0][tid] + s_psum[1][tid] + s_psum[2][tid] + s_psum[3][tid];
    float lse = lg2(tot);  // base-2 LSE
    if (joiner) {
      int r = r0 + tid;
      int t = r / 65;
      int u = r - t * 65;
      lp_blank[(b * Tn + t) * UP1 + u] = s_blank[tid] - lse;   // base-2 units
      if (u < Un) lp_label[(b * Tn + t) * Un + u] = s_label[tid] - lse;
    } else {
      ctc_blank[g0 + tid] = s_blank[tid] - lse;                // base-2 units
      ctc_lse[g0 + tid] = lse;
    }
  }
}

// ---------------------------------------------------------------------------
// K3 k_dp: blocks 0-3 RNNT anti-diagonal DP; blocks 4-7 CTC DP.
// Base-2 inputs; native v_exp/v_log chain; *LN2 once at the atomicAdd.
// Early-exit + uniform lean bodies. NEW: the a64/a2 side-track lane-63
// cndmasks removed — updates run on all lanes; non-63 lanes hold garbage
// that is provably never read (cap/owner/cT[128] lane-63-gated). CTC tail
// keeps the `run` freeze guard.
// ---------------------------------------------------------------------------
__global__ __launch_bounds__(256) void k_dp(
    const float* __restrict__ lp_blank, const float* __restrict__ lp_label,
    const float* __restrict__ ctc_blank, const float* __restrict__ ctc_lse,
    const float* __restrict__ ctc_lab,
    const int* __restrict__ target,
    const int* __restrict__ flen, const int* __restrict__ tlen,
    float* __restrict__ out) {
  __shared__ float sA[256 * 66];             // RNNT lp_blank2[t][u], stride 66
  __shared__ __align__(16) float sB[16384];  // RNNT lp_label2 ; CTC raw2
  __shared__ float sC[256], sD[256];         // CTC blank2, lse2
  __shared__ float cT[129];
  const int tid = threadIdx.x;
  const int l = tid & 63;

  if (blockIdx.x < 4) {
    const int b = blockIdx.x;
    for (int i = tid; i < 16640; i += 256) {
      int r = i / 65, cidx = i - r * 65;
      sA[r * 66 + cidx] = lp_blank[b * 16640 + i];
    }
    {
      const f32x4* g2 = (const f32x4*)(lp_label + b * 16384);
      f32x4* s2 = (f32x4*)sB;
      for (int i = tid; i < 4096; i += 256) s2[i] = g2[i];
    }
    __syncthreads();
    if (tid < 64) {
      const int ft = flen[b], tl = tlen[b];
      const int dstar = ft - 1 + tl;
      const bool isown = (l == tl);
      const bool is64 = (tl == 64) && (l == 63);
      const int lc = (l >= 1) ? l - 1 : 0;

#define RLOAD(D0, VB, VL, VB64, VL64)                                          \
  _Pragma("unroll") for (int j = 0; j < 8; ++j) {                              \
    const int d_ = (D0) + j;                                                   \
    const int t_ = d_ - l;                                                     \
    const int tbc_ = (t_ < 1) ? 1 : (t_ > 255 ? 255 : t_);                     \
    const int tcc_ = (t_ < 0) ? 0 : (t_ > 255 ? 255 : t_);                     \
    VB[j] = sA[(tbc_ - 1) * 66 + l];                                           \
    VL[j] = (l == 0) ? NEGF : sB[tcc_ * 64 + lc];                              \
    const int t64_ = d_ - 64;                                                  \
    const int t64b_ = (t64_ < 1) ? 1 : (t64_ > 255 ? 255 : t64_);              \
    const int t64c_ = (t64_ < 0) ? 0 : (t64_ > 255 ? 255 : t64_);              \
    VB64[j] = sA[(t64b_ - 1) * 66 + 64];                                       \
    VL64[j] = sB[t64c_ * 64 + 63];                                             \
  }

      float cvb[8], cvl[8], cvb64[8], cvl64[8];
      RLOAD(1, cvb, cvl, cvb64, cvl64);
      float a = (l == 0) ? 0.0f : NEGF;
      float a64 = NEGF, cap = NEGF;
      for (int d0 = 1; d0 <= dstar; d0 += 8) {  // early exit past dstar
        float nvb[8], nvl[8], nvb64[8], nvl64[8];
        RLOAD(d0 + 8, nvb, nvl, nvb64, nvl64);  // prefetch next block
        __builtin_amdgcn_sched_barrier(0);
        const bool hashit = ((unsigned)(dstar - d0)) < 8u;  // uniform
        if (hashit) {
#pragma unroll
          for (int j = 0; j < 8; ++j) {  // full body (cap capture)
            const int d = d0 + j;
            float aleft = shfl_up1(a);
            float nw = laddexp2_(a + cvb[j], aleft + cvl[j]);
            a64 = laddexp2_(a64 + cvb64[j], a + cvl64[j]);  // lane63 valid
            a = nw;
            bool hit = (d == dstar);
            cap = (hit && isown) ? a : cap;
            cap = (hit && is64) ? a64 : cap;
          }
        } else {
#pragma unroll
          for (int j = 0; j < 8; ++j) {  // lean body
            float aleft = shfl_up1(a);
            float nw = laddexp2_(a + cvb[j], aleft + cvl[j]);
            a64 = laddexp2_(a64 + cvb64[j], a + cvl64[j]);  // lane63 valid
            a = nw;
          }
        }
        __builtin_amdgcn_sched_barrier(0);
#pragma unroll
        for (int j = 0; j < 8; ++j) {
          cvb[j] = nvb[j];
          cvl[j] = nvl[j];
          cvb64[j] = nvb64[j];
          cvl64[j] = nvl64[j];
        }
      }
#undef RLOAD
      bool owner = (tl < 64) ? isown : (l == 63);
      if (owner)
        atomicAdd(out, -0.25f * LN2 * (cap + sA[(ft - 1) * 66 + tl]));
    }
  } else {
    const int b = blockIdx.x - 4;
    {
      const f32x4* g2 = (const f32x4*)(ctc_lab + b * 16384);
      f32x4* s2 = (f32x4*)sB;
      for (int i = tid; i < 4096; i += 256) s2[i] = g2[i];
      sC[tid] = ctc_blank[b * 256 + tid];
      sD[tid] = ctc_lse[b * 256 + tid];
    }
    __syncthreads();
    if (tid < 64) {
      const int ft = flen[b], tl = tlen[b];
      const int tg = target[b * Un + l];
      const int tgp = (l >= 1) ? target[b * Un + l - 1] : -1;
      const bool skip1 = (l >= 1) && (tg != tgp);

#define CLOAD(T0, EB, E1)                                                      \
  _Pragma("unroll") for (int j = 0; j < 8; ++j) {                              \
    const int tc_ = ((T0) + j > 255) ? 255 : (T0) + j;                         \
    EB[j] = sC[tc_];                                                           \
    E1[j] = sB[tc_ * 64 + l] - sD[tc_];                                        \
  }

      float ceb[8], ce1[8];
      CLOAD(1, ceb, ce1);
      float a0 = (l == 0) ? sC[0] : NEGF;
      float a1 = (l == 0) ? (sB[0] - sD[0]) : NEGF;
      float a2 = NEGF;
      for (int t0 = 1; t0 < ft; t0 += 8) {  // early exit at ft (frozen past)
        float neb[8], ne1[8];
        CLOAD(t0 + 8, neb, ne1);
        __builtin_amdgcn_sched_barrier(0);
        const bool alive = (t0 + 8 <= ft);  // uniform: all 8 steps run
        if (alive) {
#pragma unroll
          for (int j = 0; j < 8; ++j) {  // lean body (no guards)
            float pm1 = shfl_up1(a1);
            pm1 = (l == 0) ? NEGF : pm1;
            float n0 = ceb[j] + laddexp2_(a0, pm1);
            float n1 = ce1[j] + laddexp3_2(a1, a0, skip1 ? pm1 : NEGF);
            a2 = ceb[j] + laddexp2_(a2, a1);  // lane63 valid
            a0 = n0;
            a1 = n1;
          }
        } else {
#pragma unroll
          for (int j = 0; j < 8; ++j) {  // tail body (freeze guards)
            const int t = t0 + j;
            float pm1 = shfl_up1(a1);
            pm1 = (l == 0) ? NEGF : pm1;
            float n0 = ceb[j] + laddexp2_(a0, pm1);
            float n1 = ce1[j] + laddexp3_2(a1, a0, skip1 ? pm1 : NEGF);
            float n2 = ceb[j] + laddexp2_(a2, a1);
            bool run = (t < ft);
            a0 = run ? n0 : a0;
            a1 = run ? n1 : a1;
            a2 = run ? n2 : a2;  // lane63 valid; others garbage (unread)
          }
        }
        __builtin_amdgcn_sched_barrier(0);
#pragma unroll
        for (int j = 0; j < 8; ++j) {
          ceb[j] = neb[j];
          ce1[j] = ne1[j];
        }
      }
#undef CLOAD
      cT[2 * l] = a0;
      cT[2 * l + 1] = a1;
      if (l == 63) cT[128] = a2;
      __builtin_amdgcn_s_waitcnt(0);  // intra-wave lgkm drain before readback
      if (l == 0) {
        int sl = 2 * tl;
        float ll = laddexp2_(cT[sl], cT[sl - 1]);  // base-2 units
        float lb = (ll < NEGF * 0.7f) ? 0.0f : -ll;
        atomicAdd(out, CTCW * 0.25f * LN2 * lb);
      }
    }
  }
}

// ---------------------------------------------------------------------------
extern "C" void kernel_launch(void* const* d_in, const int* in_sizes, int n_in,
                              void* d_out, int out_size, void* d_ws, size_t ws_size,
                              hipStream_t stream) {
  (void)in_sizes; (void)n_in; (void)out_size; (void)ws_size;
  const float* x_enc = (const float*)d_in[0];
  const float* x_dec = (const float*)d_in[1];
  const float* W_enc = (const float*)d_in[2];
  const float* b_enc = (const float*)d_in[3];
  const float* W_dec = (const float*)d_in[4];
  const float* b_dec = (const float*)d_in[5];
  const float* W_out = (const float*)d_in[6];
  const float* b_out = (const float*)d_in[7];
  const float* W_ctc = (const float*)d_in[8];
  const float* b_ctc = (const float*)d_in[9];
  const int* target = (const int*)d_in[10];
  const int* flen = (const int*)d_in[11];
  const int* tlen = (const int*)d_in[12];

  float* ws = (float*)d_ws;
  float* enc_lin = ws;                    // 262144
  float* dec_lin = ws + 262144;           // 66560
  float* lp_blank = ws + 328704;          // 66560
  float* lp_label = ws + 395264;          // 65536
  float* ctc_blank = ws + 460800;         // 1024
  float* ctc_lse = ws + 461824;           // 1024
  float* ctc_lab = ws + 462848;           // 65536
  unsigned short* Wt_out = (unsigned short*)(ws + 528384);  // 262144 bf16 (tiled)
  unsigned short* Wt_ctc = Wt_out + 262144;                 // 262144 bf16 (tiled)
  float* out = (float*)d_out;

  k_pre<<<dim3(169), dim3(256), 0, stream>>>(
      x_enc, x_dec, W_enc, b_enc, W_dec, b_dec, W_out, W_ctc,
      Wt_out, Wt_ctc, enc_lin, dec_lin, out);
  k_join2<<<dim3(1056), dim3(256), 0, stream>>>(
      enc_lin, dec_lin, Wt_out, b_out, x_enc, Wt_ctc, b_ctc, target,
      lp_blank, lp_label, ctc_blank, ctc_lse, ctc_lab);
  k_dp<<<dim3(8), dim3(64 * 4), 0, stream>>>(
      lp_blank, lp_label, ctc_blank, ctc_lse, ctc_lab, target, flen, tlen, out);
}

// Round 19
// 108.345 us; speedup vs baseline: 1.4588x; 1.0493x over previous
//
#include <hip/hip_runtime.h>
#include <hip/hip_bf16.h>

#define Bn 4
#define Tn 256
#define Un 64
#define UP1 65
#define Vn 1024
#define Dn 256
#define Hn 256
#define BLANKC 1023
#define NEGF (-1.0e30f)
#define CTCW 0.3f
#define R2E 1.4426950408889634f  // 1/ln2
#define LN2 0.6931471805599453f

typedef __attribute__((ext_vector_type(8))) short short8;
typedef __attribute__((ext_vector_type(4))) float f32x4;
typedef __attribute__((ext_vector_type(4))) unsigned int u32x4;

static __device__ __forceinline__ unsigned short f2bf(float f) {
  unsigned int u = __float_as_uint(f);
  u += 0x7FFFu + ((u >> 16) & 1u);
  return (unsigned short)(u >> 16);
}
static __device__ __forceinline__ unsigned int pack2bf(float a, float b) {
  return (unsigned int)f2bf(a) | ((unsigned int)f2bf(b) << 16);
}
static __device__ __forceinline__ float ftanh(float x) {
  float e = __expf(2.0f * x);
  return 1.0f - 2.0f / (e + 1.0f);
}
static __device__ __forceinline__ float ex2(float x) {
  return __builtin_amdgcn_exp2f(x);
}
static __device__ __forceinline__ float lg2(float x) {
  return __builtin_amdgcn_logf(x);
}
// base-2 logaddexp; safe for +-1e30 garbage magnitudes (max-form).
static __device__ __forceinline__ float laddexp2_(float x, float y) {
  float m = fmaxf(x, y);
  float d = y - x;
  return m + lg2(1.0f + ex2(-fabsf(d)));
}
static __device__ __forceinline__ float laddexp3_2(float a, float b, float c) {
  float m = fmaxf(fmaxf(a, b), c);
  return m + lg2(ex2(a - m) + ex2(b - m) + ex2(c - m));
}
// lane i <- lane i-1 (lane 0 gets 0; callers mask lane 0). DPP wave_shr:1.
static __device__ __forceinline__ float shfl_up1(float x) {
  int r = __builtin_amdgcn_update_dpp(0, __float_as_int(x), 0x138, 0xF, 0xF, false);
  return __int_as_float(r);
}

// ---------------------------------------------------------------------------
// K1 k_pre (fused): blocks 0-127 = W_out/W_ctc step-tiled bf16 transpose;
// blocks 128-168 = enc_lin/dec_lin MFMA linears straight from W_enc/W_dec.
// ---------------------------------------------------------------------------
__global__ __launch_bounds__(256) void k_pre(
    const float* __restrict__ x_enc, const float* __restrict__ x_dec,
    const float* __restrict__ W_enc, const float* __restrict__ b_enc,
    const float* __restrict__ W_dec, const float* __restrict__ b_dec,
    const float* __restrict__ W_out, const float* __restrict__ W_ctc,
    unsigned short* __restrict__ Wt_out, unsigned short* __restrict__ Wt_ctc,
    float* __restrict__ enc_lin, float* __restrict__ dec_lin,
    float* __restrict__ out) {
  const int blk = blockIdx.x, tid = threadIdx.x;
  if (blk == 0 && tid == 0) out[0] = 0.0f;
  const int w = tid >> 6, l = tid & 63;
  const int l15 = l & 15, l4 = l >> 4;

  if (blk < 128) {
    __shared__ float tilebuf[64][65];
    const float* Wsrc = (blk < 64) ? W_out : W_ctc;
    unsigned short* Wd = (blk < 64) ? Wt_out : Wt_ctc;
    const int tt = blk & 63;
    const int k0 = (tt & 3) * 64, v0 = (tt >> 2) * 64;
#pragma unroll
    for (int rep = 0; rep < 16; ++rep) {
      int e = rep * 256 + tid;
      int rr = e >> 6, cc = e & 63;  // rr: k-off, cc: n-off
      tilebuf[rr][cc] = Wsrc[(k0 + rr) * 1024 + (v0 + cc)];
    }
    __syncthreads();
#pragma unroll
    for (int rep = 0; rep < 16; ++rep) {
      int e = rep * 256 + tid;
      int nn = e >> 6, kk = e & 63;
      int n = v0 + nn, k = k0 + kk;
      int c = n >> 8, col = n & 255;
      int ks = k >> 5, sub = (k >> 3) & 3, k7 = k & 7;
      Wd[(c * 8 + ks) * 8192 + sub * 2048 + col * 8 + k7] = f2bf(tilebuf[kk][nn]);
    }
  } else {
    // ---- linear part (32-row tiles): blocks 128-159 enc, 160-168 dec ----
    __shared__ __align__(16) char Asw[32 * 512];
    const int lb = blk - 128;
    const bool enc = lb < 32;
    const int m0 = enc ? lb * 32 : (lb - 32) * 32;
    const int Mlim = enc ? 1024 : 260;
    const float* xp = enc ? x_enc : x_dec;
    const float* Wsrc = enc ? W_enc : W_dec;
    const float* bias = enc ? b_enc : b_dec;
    float* outp = enc ? enc_lin : dec_lin;

#pragma unroll
    for (int it = 0; it < 4; ++it) {
      int e = (it << 8) + tid;
      int i = e >> 5;                 // row 0..31
      int k0 = (e & 31) << 3;
      int r = m0 + i;
      if (r > Mlim - 1) r = Mlim - 1;
      const float* sp = xp + r * 256 + k0;
      f32x4 e0 = *(const f32x4*)sp;
      f32x4 e1 = *(const f32x4*)(sp + 4);
      u32x4 pv;
      pv[0] = pack2bf(e0[0], e0[1]);
      pv[1] = pack2bf(e0[2], e0[3]);
      pv[2] = pack2bf(e1[0], e1[1]);
      pv[3] = pack2bf(e1[2], e1[3]);
      int byt = (i << 9) + (k0 << 1);
      byt ^= (i & 7) << 4;
      *(u32x4*)(Asw + byt) = pv;
    }
    __syncthreads();

    const int nb = w * 64;
    f32x4 acc[2][4] = {};
#pragma unroll
    for (int ks = 0; ks < 8; ++ks) {
      int k = ks * 32 + l4 * 8;
      short8 af[2];
#pragma unroll
      for (int mt = 0; mt < 2; ++mt) {
        int i = mt * 16 + l15;
        int byt = (i << 9) + (k << 1);
        byt ^= (i & 7) << 4;
        af[mt] = *(const short8*)(Asw + byt);
      }
      short8 bfr[4];
#pragma unroll
      for (int nt = 0; nt < 4; ++nt) {
        int n = nb + nt * 16 + l15;
        const float* wp = Wsrc + k * 256 + n;
        short8 v;
#pragma unroll
        for (int j = 0; j < 8; ++j) v[j] = (short)f2bf(wp[j * 256]);
        bfr[nt] = v;
      }
#pragma unroll
      for (int mt = 0; mt < 2; ++mt)
#pragma unroll
        for (int nt = 0; nt < 4; ++nt)
          acc[mt][nt] = __builtin_amdgcn_mfma_f32_16x16x32_bf16(
              af[mt], bfr[nt], acc[mt][nt], 0, 0, 0);
    }
    float biasv[4];
#pragma unroll
    for (int nt = 0; nt < 4; ++nt) biasv[nt] = bias[nb + nt * 16 + l15];
#pragma unroll
    for (int mt = 0; mt < 2; ++mt)
#pragma unroll
      for (int rr = 0; rr < 4; ++rr) {
        int row = m0 + mt * 16 + l4 * 4 + rr;
        if (row < Mlim) {
#pragma unroll
          for (int nt = 0; nt < 4; ++nt)
            outp[row * 256 + nb + nt * 16 + l15] = acc[mt][nt][rr] + biasv[nt];
        }
      }
  }
}

// ---------------------------------------------------------------------------
// K2 merged: blocks 0-15 = CTC head; blocks 16-1055 = joiner.
// Measured-best structure + NEW L1-SHARING rotation key: cc uses (bid>>2)&3
// so each aligned group of 4 consecutive blocks (the likely co-residents of
// one CU) walks the SAME step sequence -> B loads L1-hit for 3 of 4 blocks;
// groups remain de-phased across CUs for L2-slice spreading.
// ---------------------------------------------------------------------------
__global__ __launch_bounds__(256) void k_join2(
    const float* __restrict__ enc_lin, const float* __restrict__ dec_lin,
    const unsigned short* __restrict__ Wt_out, const float* __restrict__ b_out,
    const float* __restrict__ x_enc,
    const unsigned short* __restrict__ Wt_ctc, const float* __restrict__ b_ctc,
    const int* __restrict__ target,
    float* __restrict__ lp_blank, float* __restrict__ lp_label,
    float* __restrict__ ctc_blank, float* __restrict__ ctc_lse,
    float* __restrict__ ctc_lab) {
  __shared__ __align__(16) char Asw[64 * 512];    // 32KB A tile
  __shared__ float s_psum[4][64];
  __shared__ float s_blank[64], s_label[64];
  __shared__ int s_tgt[64];

  const int tid = threadIdx.x;
  const int w = tid >> 6, l = tid & 63;
  const int l15 = l & 15, l4 = l >> 4;
  const int bid = blockIdx.x;
  const int rotk = (bid >> 2) & 3;  // group-of-4 rotation key (L1 sharing)

  const bool joiner = bid >= 16;
  const unsigned short* Wt = joiner ? Wt_out : Wt_ctc;
  const float* bias = joiner ? b_out : b_ctc;

  // B base: step s, col = w*64 + nt*16 + l15, sub = l4.
  const unsigned short* tb = Wt + l4 * 2048 + (w * 64 + l15) * 8;

  short8 bE[4], bO[4];
#define LOADB(REG, S)                                                          \
  {                                                                            \
    const unsigned short* p_ = tb + (S)*8192;                                  \
    _Pragma("unroll") for (int nt = 0; nt < 4; ++nt)                           \
        REG[nt] = *(const short8*)(p_ + nt * 128);                             \
  }
  {
    const int sc0 = rotk * 8;
    LOADB(bE, sc0 + 0)
    LOADB(bO, sc0 + 1)
  }

  int b, r0 = 0, g0 = 0;
  if (joiner) {
    const int jbid = bid - 16;
    b = jbid / 260;
    r0 = (jbid % 260) * 64;
#pragma unroll
    for (int it = 0; it < 8; ++it) {
      int e = (it << 8) + tid;
      int i = e >> 5;
      int k0 = (e & 31) << 3;
      int r = r0 + i;
      int t = r / 65;
      int u = r - t * 65;
      const float* ep = enc_lin + ((b * Tn + t) * Hn + k0);
      const float* dp = dec_lin + ((b * UP1 + u) * Hn + k0);
      f32x4 e0 = *(const f32x4*)ep;
      f32x4 e1 = *(const f32x4*)(ep + 4);
      f32x4 d0 = *(const f32x4*)dp;
      f32x4 d1 = *(const f32x4*)(dp + 4);
      u32x4 pv;
      pv[0] = pack2bf(ftanh(e0[0] + d0[0]) * R2E, ftanh(e0[1] + d0[1]) * R2E);
      pv[1] = pack2bf(ftanh(e0[2] + d0[2]) * R2E, ftanh(e0[3] + d0[3]) * R2E);
      pv[2] = pack2bf(ftanh(e1[0] + d1[0]) * R2E, ftanh(e1[1] + d1[1]) * R2E);
      pv[3] = pack2bf(ftanh(e1[2] + d1[2]) * R2E, ftanh(e1[3] + d1[3]) * R2E);
      int byt = (i << 9) + (k0 << 1);
      byt ^= (i & 7) << 4;
      *(u32x4*)(Asw + byt) = pv;
    }
    if (tid < 64) {
      int u = (r0 + tid) % 65;
      s_tgt[tid] = (u < Un) ? target[b * Un + u] : -1;
    }
  } else {
    g0 = bid * 64;
    b = g0 >> 8;
#pragma unroll
    for (int it = 0; it < 8; ++it) {
      int e = (it << 8) + tid;
      int i = e >> 5;
      int k0 = (e & 31) << 3;
      const float* sp = x_enc + (g0 + i) * Dn + k0;
      f32x4 e0 = *(const f32x4*)sp;
      f32x4 e1 = *(const f32x4*)(sp + 4);
      u32x4 pv;
      pv[0] = pack2bf(e0[0] * R2E, e0[1] * R2E);
      pv[1] = pack2bf(e0[2] * R2E, e0[3] * R2E);
      pv[2] = pack2bf(e1[0] * R2E, e1[1] * R2E);
      pv[3] = pack2bf(e1[2] * R2E, e1[3] * R2E);
      int byt = (i << 9) + (k0 << 1);
      byt ^= (i & 7) << 4;
      *(u32x4*)(Asw + byt) = pv;
    }
    if (tid < 64) s_tgt[tid] = target[b * Un + tid];
  }
  __syncthreads();  // A tile + s_tgt ready; the ONLY pre-epilogue barrier

  float ssum[16];
#pragma unroll
  for (int j = 0; j < 16; ++j) ssum[j] = 0.0f;

#define MFMASTEP(REG, KS)                                                      \
  {                                                                            \
    const int k_ = (KS)*32 + l4 * 8;                                           \
    _Pragma("unroll") for (int mt = 0; mt < 4; ++mt) {                         \
      int i_ = mt * 16 + l15;                                                  \
      int byt_ = ((i_ << 9) + (k_ << 1)) ^ ((i_ & 7) << 4);                    \
      short8 af_ = *(const short8*)(Asw + byt_);                               \
      _Pragma("unroll") for (int nt = 0; nt < 4; ++nt)                         \
          acc[mt][nt] = __builtin_amdgcn_mfma_f32_16x16x32_bf16(               \
              af_, REG[nt], acc[mt][nt], 0, 0, 0);                             \
    }                                                                          \
  }
#define SB __builtin_amdgcn_sched_barrier(0)

#pragma unroll 1
  for (int cr = 0; cr < 4; ++cr) {
    const int cc = (cr + rotk) & 3;             // rotated chunk id (uniform)
    const int sc = cc * 8;
    const int scn = ((cr + 1 + rotk) & 3) * 8;  // next chunk's step base
    f32x4 acc[4][4] = {};
    MFMASTEP(bE, 0) LOADB(bE, sc + 2) SB;
    MFMASTEP(bO, 1) LOADB(bO, sc + 3) SB;
    MFMASTEP(bE, 2) LOADB(bE, sc + 4) SB;
    MFMASTEP(bO, 3) LOADB(bO, sc + 5) SB;
    MFMASTEP(bE, 4) LOADB(bE, sc + 6) SB;
    MFMASTEP(bO, 5) LOADB(bO, sc + 7) SB;
    MFMASTEP(bE, 6) LOADB(bE, (cr < 3) ? scn + 0 : sc + 6) SB;
    MFMASTEP(bO, 7) LOADB(bO, (cr < 3) ? scn + 1 : sc + 7) SB;

    const int nb = cc * 256 + w * 64;
    float biasv[4];
#pragma unroll
    for (int nt = 0; nt < 4; ++nt) biasv[nt] = bias[nb + nt * 16 + l15] * R2E;
#pragma unroll
    for (int mt = 0; mt < 4; ++mt)
#pragma unroll
      for (int nt = 0; nt < 4; ++nt)
#pragma unroll
        for (int rr = 0; rr < 4; ++rr) acc[mt][nt][rr] += biasv[nt];

    if (joiner) {
      if (cc == 3 && w == 3 && l15 == 15) {
#pragma unroll
        for (int mt = 0; mt < 4; ++mt)
#pragma unroll
          for (int rr = 0; rr < 4; ++rr)
            s_blank[mt * 16 + l4 * 4 + rr] = acc[mt][3][rr];
      }
#pragma unroll
      for (int mt = 0; mt < 4; ++mt)
#pragma unroll
        for (int rr = 0; rr < 4; ++rr) {
          int row = mt * 16 + l4 * 4 + rr;
          int tg = s_tgt[row];
          if ((tg >> 8) == cc && ((tg >> 6) & 3) == w && (tg & 15) == l15) {
            int ntv = (tg >> 4) & 3;
            float v01 = (ntv & 1) ? acc[mt][1][rr] : acc[mt][0][rr];
            float v23 = (ntv & 1) ? acc[mt][3][rr] : acc[mt][2][rr];
            s_label[row] = (ntv & 2) ? v23 : v01;
          }
        }
    } else {
      if (cc == 3 && w == 3 && l15 == 15) {
#pragma unroll
        for (int mt = 0; mt < 4; ++mt)
#pragma unroll
          for (int rr = 0; rr < 4; ++rr)
            s_blank[mt * 16 + l4 * 4 + rr] = acc[mt][3][rr];
      }
#pragma unroll 1
      for (int u = 0; u < 64; ++u) {
        int tgu = s_tgt[u];
        if ((tgu >> 8) == cc && ((tgu >> 6) & 3) == w) {
          int ntv = (tgu >> 4) & 3;
          if ((tgu & 15) == l15) {
#pragma unroll
            for (int mt = 0; mt < 4; ++mt)
#pragma unroll
              for (int rr = 0; rr < 4; ++rr) {
                float v01 = (ntv & 1) ? acc[mt][1][rr] : acc[mt][0][rr];
                float v23 = (ntv & 1) ? acc[mt][3][rr] : acc[mt][2][rr];
                float v = (ntv & 2) ? v23 : v01;
                ctc_lab[(g0 + mt * 16 + l4 * 4 + rr) * 64 + u] = v;
              }
          }
        }
      }
    }
    // base-2 exp-sum: acc already in log2 units, raw v_exp (no mul)
#pragma unroll
    for (int mt = 0; mt < 4; ++mt)
#pragma unroll
      for (int rr = 0; rr < 4; ++rr)
        ssum[mt * 4 + rr] += ex2(acc[mt][0][rr]) + ex2(acc[mt][1][rr]) +
                             ex2(acc[mt][2][rr]) + ex2(acc[mt][3][rr]);
  }
#undef MFMASTEP
#undef LOADB
#undef SB

#pragma unroll
  for (int ms = 1; ms < 16; ms <<= 1)
#pragma unroll
    for (int j = 0; j < 16; ++j) ssum[j] += __shfl_xor(ssum[j], ms, 64);
  if (l15 == 0) {
#pragma unroll
    for (int j = 0; j < 16; ++j)
      s_psum[w][(j >> 2) * 16 + l4 * 4 + (j & 3)] = ssum[j];
  }
  __syncthreads();

  if (tid < 64) {
    float tot = s_psum[0][tid] + s_psum[1][tid] + s_psum[2][tid] + s_psum[3][tid];
    float lse = lg2(tot);  // base-2 LSE
    if (joiner) {
      int r = r0 + tid;
      int t = r / 65;
      int u = r - t * 65;
      lp_blank[(b * Tn + t) * UP1 + u] = s_blank[tid] - lse;   // base-2 units
      if (u < Un) lp_label[(b * Tn + t) * Un + u] = s_label[tid] - lse;
    } else {
      ctc_blank[g0 + tid] = s_blank[tid] - lse;                // base-2 units
      ctc_lse[g0 + tid] = lse;
    }
  }
}

// ---------------------------------------------------------------------------
// K3 k_dp: blocks 0-3 RNNT anti-diagonal DP; blocks 4-7 CTC DP.
// 512 threads: preload (66KB+64KB) in half the time; chain on wave 0.
// Base-2 inputs; early-exit + uniform lean bodies; side-tracks unmasked
// (garbage lanes provably unread).
// ---------------------------------------------------------------------------
__global__ __launch_bounds__(512) void k_dp(
    const float* __restrict__ lp_blank, const float* __restrict__ lp_label,
    const float* __restrict__ ctc_blank, const float* __restrict__ ctc_lse,
    const float* __restrict__ ctc_lab,
    const int* __restrict__ target,
    const int* __restrict__ flen, const int* __restrict__ tlen,
    float* __restrict__ out) {
  __shared__ float sA[256 * 66];             // RNNT lp_blank2[t][u], stride 66
  __shared__ __align__(16) float sB[16384];  // RNNT lp_label2 ; CTC raw2
  __shared__ float sC[256], sD[256];         // CTC blank2, lse2
  __shared__ float cT[129];
  const int tid = threadIdx.x;
  const int l = tid & 63;

  if (blockIdx.x < 4) {
    const int b = blockIdx.x;
    for (int i = tid; i < 16640; i += 512) {
      int r = i / 65, cidx = i - r * 65;
      sA[r * 66 + cidx] = lp_blank[b * 16640 + i];
    }
    {
      const f32x4* g2 = (const f32x4*)(lp_label + b * 16384);
      f32x4* s2 = (f32x4*)sB;
      for (int i = tid; i < 4096; i += 512) s2[i] = g2[i];
    }
    __syncthreads();
    if (tid < 64) {
      const int ft = flen[b], tl = tlen[b];
      const int dstar = ft - 1 + tl;
      const bool isown = (l == tl);
      const bool is64 = (tl == 64) && (l == 63);
      const int lc = (l >= 1) ? l - 1 : 0;

#define RLOAD(D0, VB, VL, VB64, VL64)                                          \
  _Pragma("unroll") for (int j = 0; j < 8; ++j) {                              \
    const int d_ = (D0) + j;                                                   \
    const int t_ = d_ - l;                                                     \
    const int tbc_ = (t_ < 1) ? 1 : (t_ > 255 ? 255 : t_);                     \
    const int tcc_ = (t_ < 0) ? 0 : (t_ > 255 ? 255 : t_);                     \
    VB[j] = sA[(tbc_ - 1) * 66 + l];                                           \
    VL[j] = (l == 0) ? NEGF : sB[tcc_ * 64 + lc];                              \
    const int t64_ = d_ - 64;                                                  \
    const int t64b_ = (t64_ < 1) ? 1 : (t64_ > 255 ? 255 : t64_);              \
    const int t64c_ = (t64_ < 0) ? 0 : (t64_ > 255 ? 255 : t64_);              \
    VB64[j] = sA[(t64b_ - 1) * 66 + 64];                                       \
    VL64[j] = sB[t64c_ * 64 + 63];                                             \
  }

      float cvb[8], cvl[8], cvb64[8], cvl64[8];
      RLOAD(1, cvb, cvl, cvb64, cvl64);
      float a = (l == 0) ? 0.0f : NEGF;
      float a64 = NEGF, cap = NEGF;
      for (int d0 = 1; d0 <= dstar; d0 += 8) {  // early exit past dstar
        float nvb[8], nvl[8], nvb64[8], nvl64[8];
        RLOAD(d0 + 8, nvb, nvl, nvb64, nvl64);  // prefetch next block
        __builtin_amdgcn_sched_barrier(0);
        const bool hashit = ((unsigned)(dstar - d0)) < 8u;  // uniform
        if (hashit) {
#pragma unroll
          for (int j = 0; j < 8; ++j) {  // full body (cap capture)
            const int d = d0 + j;
            float aleft = shfl_up1(a);
            float nw = laddexp2_(a + cvb[j], aleft + cvl[j]);
            a64 = laddexp2_(a64 + cvb64[j], a + cvl64[j]);  // lane63 valid
            a = nw;
            bool hit = (d == dstar);
            cap = (hit && isown) ? a : cap;
            cap = (hit && is64) ? a64 : cap;
          }
        } else {
#pragma unroll
          for (int j = 0; j < 8; ++j) {  // lean body
            float aleft = shfl_up1(a);
            float nw = laddexp2_(a + cvb[j], aleft + cvl[j]);
            a64 = laddexp2_(a64 + cvb64[j], a + cvl64[j]);  // lane63 valid
            a = nw;
          }
        }
        __builtin_amdgcn_sched_barrier(0);
#pragma unroll
        for (int j = 0; j < 8; ++j) {
          cvb[j] = nvb[j];
          cvl[j] = nvl[j];
          cvb64[j] = nvb64[j];
          cvl64[j] = nvl64[j];
        }
      }
#undef RLOAD
      bool owner = (tl < 64) ? isown : (l == 63);
      if (owner)
        atomicAdd(out, -0.25f * LN2 * (cap + sA[(ft - 1) * 66 + tl]));
    }
  } else {
    const int b = blockIdx.x - 4;
    {
      const f32x4* g2 = (const f32x4*)(ctc_lab + b * 16384);
      f32x4* s2 = (f32x4*)sB;
      for (int i = tid; i < 4096; i += 512) s2[i] = g2[i];
      if (tid < 256) {
        sC[tid] = ctc_blank[b * 256 + tid];
        sD[tid] = ctc_lse[b * 256 + tid];
      }
    }
    __syncthreads();
    if (tid < 64) {
      const int ft = flen[b], tl = tlen[b];
      const int tg = target[b * Un + l];
      const int tgp = (l >= 1) ? target[b * Un + l - 1] : -1;
      const bool skip1 = (l >= 1) && (tg != tgp);

#define CLOAD(T0, EB, E1)                                                      \
  _Pragma("unroll") for (int j = 0; j < 8; ++j) {                              \
    const int tc_ = ((T0) + j > 255) ? 255 : (T0) + j;                         \
    EB[j] = sC[tc_];                                                           \
    E1[j] = sB[tc_ * 64 + l] - sD[tc_];                                        \
  }

      float ceb[8], ce1[8];
      CLOAD(1, ceb, ce1);
      float a0 = (l == 0) ? sC[0] : NEGF;
      float a1 = (l == 0) ? (sB[0] - sD[0]) : NEGF;
      float a2 = NEGF;
      for (int t0 = 1; t0 < ft; t0 += 8) {  // early exit at ft (frozen past)
        float neb[8], ne1[8];
        CLOAD(t0 + 8, neb, ne1);
        __builtin_amdgcn_sched_barrier(0);
        const bool alive = (t0 + 8 <= ft);  // uniform: all 8 steps run
        if (alive) {
#pragma unroll
          for (int j = 0; j < 8; ++j) {  // lean body (no guards)
            float pm1 = shfl_up1(a1);
            pm1 = (l == 0) ? NEGF : pm1;
            float n0 = ceb[j] + laddexp2_(a0, pm1);
            float n1 = ce1[j] + laddexp3_2(a1, a0, skip1 ? pm1 : NEGF);
            a2 = ceb[j] + laddexp2_(a2, a1);  // lane63 valid
            a0 = n0;
            a1 = n1;
          }
        } else {
#pragma unroll
          for (int j = 0; j < 8; ++j) {  // tail body (freeze guards)
            const int t = t0 + j;
            float pm1 = shfl_up1(a1);
            pm1 = (l == 0) ? NEGF : pm1;
            float n0 = ceb[j] + laddexp2_(a0, pm1);
            float n1 = ce1[j] + laddexp3_2(a1, a0, skip1 ? pm1 : NEGF);
            float n2 = ceb[j] + laddexp2_(a2, a1);
            bool run = (t < ft);
            a0 = run ? n0 : a0;
            a1 = run ? n1 : a1;
            a2 = run ? n2 : a2;  // lane63 valid; others garbage (unread)
          }
        }
        __builtin_amdgcn_sched_barrier(0);
#pragma unroll
        for (int j = 0; j < 8; ++j) {
          ceb[j] = neb[j];
          ce1[j] = ne1[j];
        }
      }
#undef CLOAD
      cT[2 * l] = a0;
      cT[2 * l + 1] = a1;
      if (l == 63) cT[128] = a2;
      __builtin_amdgcn_s_waitcnt(0);  // intra-wave lgkm drain before readback
      if (l == 0) {
        int sl = 2 * tl;
        float ll = laddexp2_(cT[sl], cT[sl - 1]);  // base-2 units
        float lb = (ll < NEGF * 0.7f) ? 0.0f : -ll;
        atomicAdd(out, CTCW * 0.25f * LN2 * lb);
      }
    }
  }
}

// ---------------------------------------------------------------------------
extern "C" void kernel_launch(void* const* d_in, const int* in_sizes, int n_in,
                              void* d_out, int out_size, void* d_ws, size_t ws_size,
                              hipStream_t stream) {
  (void)in_sizes; (void)n_in; (void)out_size; (void)ws_size;
  const float* x_enc = (const float*)d_in[0];
  const float* x_dec = (const float*)d_in[1];
  const float* W_enc = (const float*)d_in[2];
  const float* b_enc = (const float*)d_in[3];
  const float* W_dec = (const float*)d_in[4];
  const float* b_dec = (const float*)d_in[5];
  const float* W_out = (const float*)d_in[6];
  const float* b_out = (const float*)d_in[7];
  const float* W_ctc = (const float*)d_in[8];
  const float* b_ctc = (const float*)d_in[9];
  const int* target = (const int*)d_in[10];
  const int* flen = (const int*)d_in[11];
  const int* tlen = (const int*)d_in[12];

  float* ws = (float*)d_ws;
  float* enc_lin = ws;                    // 262144
  float* dec_lin = ws + 262144;           // 66560
  float* lp_blank = ws + 328704;          // 66560
  float* lp_label = ws + 395264;          // 65536
  float* ctc_blank = ws + 460800;         // 1024
  float* ctc_lse = ws + 461824;           // 1024
  float* ctc_lab = ws + 462848;           // 65536
  unsigned short* Wt_out = (unsigned short*)(ws + 528384);  // 262144 bf16 (tiled)
  unsigned short* Wt_ctc = Wt_out + 262144;                 // 262144 bf16 (tiled)
  float* out = (float*)d_out;

  k_pre<<<dim3(169), dim3(256), 0, stream>>>(
      x_enc, x_dec, W_enc, b_enc, W_dec, b_dec, W_out, W_ctc,
      Wt_out, Wt_ctc, enc_lin, dec_lin, out);
  k_join2<<<dim3(1056), dim3(256), 0, stream>>>(
      enc_lin, dec_lin, Wt_out, b_out, x_enc, Wt_ctc, b_ctc, target,
      lp_blank, lp_label, ctc_blank, ctc_lse, ctc_lab);
  k_dp<<<dim3(8), dim3(512), 0, stream>>>(
      lp_blank, lp_label, ctc_blank, ctc_lse, ctc_lab, target, flen, tlen, out);
}